// Round 8
// baseline (355.977 us; speedup 1.0000x reference)
//
#include <hip/hip_runtime.h>
#include <hip/hip_fp16.h>
#include <cstddef>

#define HID 64
#define CLS 40

__device__ __forceinline__ float lrelu(float x) { return x >= 0.f ? x : 0.2f * x; }

__device__ __forceinline__ float wmax32(float v) {
#pragma unroll
    for (int o = 16; o > 0; o >>= 1) v = fmaxf(v, __shfl_xor(v, o));
    return v;
}
__device__ __forceinline__ float wsum32(float v) {
#pragma unroll
    for (int o = 16; o > 0; o >>= 1) v += __shfl_xor(v, o);
    return v;
}

// ---------------- degree init (0; self-loop occupies LAST slot) ----------------
__global__ __launch_bounds__(256) void k_deginit(int* degS, int* degD, int n) {
    int i = blockIdx.x * 256 + threadIdx.x;
    if (i < n) { degS[i] = 0; degD[i] = 0; }
}

// ---------------- GEMM body: 64 rows/block, 4 threads/row ----------------
// W staged in LDS, row stride K+4, seg-interleaved columns (2-way conflict = free).
// Writes R replicated copies of the fp16 H row (one per XCD consumer).
template <int K, bool APPLY>
__device__ __forceinline__ void gemm_body(const float* __restrict__ X,
                                          const float* __restrict__ W,
                                          const float* __restrict__ aw,
                                          const float* __restrict__ sw,
                                          const int* __restrict__ degS,
                                          const int* __restrict__ degD,
                                          __half* __restrict__ Hh, size_t hN, int R,
                                          float* __restrict__ ds,
                                          float* __restrict__ dssw,
                                          float2* __restrict__ dtp,
                                          float* __restrict__ dtraw,
                                          float* __restrict__ d2raw,
                                          float* __restrict__ d3raw,
                                          int n, int brow, int tid) {
    constexpr int STR = K + 4;
    __shared__ float Wl[HID * STR];
    __shared__ float awl[128];
    __shared__ float swl[128];
    for (int i = tid; i < HID * K; i += 256) {
        int c = i / K, k = i % K;
        Wl[c * STR + k] = W[i];
    }
    if (tid < 128) awl[tid] = aw[tid];
    else swl[tid - 128] = sw[tid - 128];
    __syncthreads();
    int r = brow * 64 + (tid >> 2);
    int seg = tid & 3;
    if (r >= n) return;
    float acc[16];
#pragma unroll
    for (int c = 0; c < 16; c++) acc[c] = 0.f;
    const float* xr = X + (size_t)r * K;
    const float* wb = &Wl[4 * seg * STR];
    for (int k = 0; k < K; k += 4) {
        float4 xv = *reinterpret_cast<const float4*>(xr + k);
#pragma unroll
        for (int c = 0; c < 16; c++) {
            int crel = 16 * (c >> 2) + (c & 3);
            float4 wv = *reinterpret_cast<const float4*>(wb + crel * STR + k);
            acc[c] += xv.x * wv.x + xv.y * wv.y + xv.z * wv.z + xv.w * wv.w;
        }
    }
    float d0 = 0.f, d1 = 0.f, d2 = 0.f, d3 = 0.f;
#pragma unroll
    for (int c = 0; c < 16; c++) {
        int cc = 16 * (c >> 2) + 4 * seg + (c & 3);
        d0 += acc[c] * awl[cc];
        d1 += acc[c] * awl[64 + cc];
        d2 += acc[c] * swl[cc];
        d3 += acc[c] * swl[64 + cc];
    }
    uint2 stv[4];
#pragma unroll
    for (int t = 0; t < 4; t++) {
        union { __half2 h2[2]; uint2 u; } st;
        st.h2[0] = __floats2half2_rn(acc[4 * t], acc[4 * t + 1]);
        st.h2[1] = __floats2half2_rn(acc[4 * t + 2], acc[4 * t + 3]);
        stv[t] = st.u;
    }
    for (int rep = 0; rep < R; rep++) {
        __half* hb = Hh + (size_t)rep * hN + (size_t)r * HID + 4 * seg;
#pragma unroll
        for (int t = 0; t < 4; t++)
            *reinterpret_cast<uint2*>(hb + 16 * t) = stv[t];
    }
    // quad reduce (threads 4q..4q+3 share row r)
    d0 += __shfl_xor(d0, 1); d0 += __shfl_xor(d0, 2);
    d1 += __shfl_xor(d1, 1); d1 += __shfl_xor(d1, 2);
    d2 += __shfl_xor(d2, 1); d2 += __shfl_xor(d2, 2);
    d3 += __shfl_xor(d3, 1); d3 += __shfl_xor(d3, 2);
    if (seg == 0) {
        ds[r] = d0;
        if (APPLY) {
            dssw[r] = (float)(degS[r] + 1) * d2;
            float2 v = make_float2(d1, (float)(degD[r] + 1) * d3);
            for (int rep = 0; rep < 8; rep++) dtp[(size_t)rep * n + r] = v;
        } else {
            dtraw[r] = d1;
            d2raw[r] = d2;
            d3raw[r] = d3;
        }
    }
}

// ---------------- fused: layer-0 GEMM (independent) + degree count/rank ----------------
__global__ __launch_bounds__(256) void k_fused0(const float* __restrict__ x,
                                                const float* __restrict__ w0,
                                                const float* __restrict__ aw,
                                                const float* __restrict__ sw,
                                                __half* __restrict__ Hh, size_t hN, int R,
                                                float* __restrict__ ds,
                                                float* __restrict__ dtraw,
                                                float* __restrict__ d2raw,
                                                float* __restrict__ d3raw,
                                                const int* __restrict__ ei,
                                                int* degS, int* degD,
                                                unsigned* __restrict__ ranks,
                                                int n, int E, int gb) {
    if ((int)blockIdx.x < gb) {
        gemm_body<128, false>(x, w0, aw, sw, nullptr, nullptr, Hh, hN, R, ds,
                              nullptr, nullptr, dtraw, d2raw, d3raw,
                              n, blockIdx.x, threadIdx.x);
    } else {
        int t = (blockIdx.x - gb) * 256 + threadIdx.x;
        int stride = (gridDim.x - gb) * 256;
        for (int e = t; e < E; e += stride) {
            int s = ei[e], d = ei[E + e];
            unsigned rs = (unsigned)atomicAdd(&degS[s], 1);
            unsigned rd = (unsigned)atomicAdd(&degD[d], 1);
            ranks[e] = rs | (rd << 16);  // deg < 65536
        }
    }
}

// ---------------- layer-1 GEMM ----------------
__global__ __launch_bounds__(256) void k_gemm1(const float* __restrict__ X,
                                               const float* __restrict__ W,
                                               const float* __restrict__ aw,
                                               const float* __restrict__ sw,
                                               const int* __restrict__ degS,
                                               const int* __restrict__ degD,
                                               __half* __restrict__ Hh, size_t hN, int R,
                                               float* __restrict__ ds,
                                               float* __restrict__ dssw,
                                               float2* __restrict__ dtp,
                                               int n) {
    gemm_body<64, true>(X, W, aw, sw, degS, degD, Hh, hN, R, ds, dssw, dtp,
                        nullptr, nullptr, nullptr, n, blockIdx.x, threadIdx.x);
}

// ---------------- combined scans: S (blocks 0..nb-1) and D (nb..2nb-1) ----------------
__global__ __launch_bounds__(1024) void k_scanA(const int* __restrict__ degS,
                                                const int* __restrict__ degD,
                                                const float* __restrict__ d2raw,
                                                const float* __restrict__ d3raw,
                                                const float* __restrict__ dtraw,
                                                int* __restrict__ offS,
                                                int* __restrict__ offD,
                                                int* __restrict__ bsum,
                                                float* __restrict__ dssw,
                                                float2* __restrict__ dtp,
                                                int n, int nb) {
    __shared__ int buf[2][1024];
    int which = (int)blockIdx.x >= nb;
    const int* deg = which ? degD : degS;
    int* off = which ? offD : offS;
    int b = blockIdx.x - (which ? nb : 0);
    int tid = threadIdx.x;
    int i = b * 1024 + tid;
    int v = (i < n) ? deg[i] + 1 : 0;
    int cur = 0;
    buf[0][tid] = v;
    __syncthreads();
#pragma unroll
    for (int o = 1; o < 1024; o <<= 1) {
        int t = buf[cur][tid];
        if (tid >= o) t += buf[cur][tid - o];
        buf[cur ^ 1][tid] = t;
        cur ^= 1;
        __syncthreads();
    }
    if (i < n) off[i] = buf[cur][tid];
    if (tid == 1023) bsum[which * 64 + b] = buf[cur][1023];
    if (!which && i < n) {
        dssw[i] = (float)(degS[i] + 1) * d2raw[i];
        float2 vv = make_float2(dtraw[i], (float)(degD[i] + 1) * d3raw[i]);
        for (int rep = 0; rep < 8; rep++) dtp[(size_t)rep * n + i] = vv;
    }
}

__global__ void k_scanB(int* bsum, int nb) {
    int t = threadIdx.x;
    if (t < 2) {
        int run = 0;
        for (int b = 0; b < nb; b++) {
            int x = bsum[t * 64 + b];
            bsum[t * 64 + b] = run;
            run += x;
        }
    }
}

__global__ __launch_bounds__(1024) void k_scanC(const int* __restrict__ degS,
                                                const int* __restrict__ degD,
                                                int* __restrict__ offS,
                                                int* __restrict__ offD,
                                                const int* __restrict__ bsum,
                                                int n, int total, int nb) {
    int which = (int)blockIdx.x >= nb;
    const int* deg = which ? degD : degS;
    int* off = which ? offD : offS;
    int b = blockIdx.x - (which ? nb : 0);
    int i = b * 1024 + threadIdx.x;
    if (i < n) off[i] = off[i] - (deg[i] + 1) + bsum[which * 64 + b];
    if (i == 0) off[n] = total;
}

// ---------------- scatter: XCD-partitioned, atomic-free ----------------
// csrS[slotS] = {dst, norm_bits};  csrD[slotD] = {src, norm_bits}
// self-loop takes the LAST slot of each segment.
__global__ __launch_bounds__(256) void k_scatter(const int* __restrict__ ei,
                                                 const float* __restrict__ norm,
                                                 const int* __restrict__ offS,
                                                 const int* __restrict__ offD,
                                                 const unsigned* __restrict__ ranks,
                                                 int2* __restrict__ csrS,
                                                 int2* __restrict__ csrD,
                                                 int Et, int E, int N) {
    int grp = blockIdx.x & 7;
    int lo = (int)(((long long)grp * N) / 8);
    int hi = (int)(((long long)(grp + 1) * N) / 8);
    int start = (blockIdx.x >> 3) * 256 + threadIdx.x;
    int stride = (gridDim.x >> 3) * 256;
    for (int e = start; e < Et; e += stride) {
        int s, d, slotS, slotD;
        if (e < E) {
            s = ei[e]; d = ei[E + e];
            unsigned ur = ranks[e];
            slotS = offS[s] + (int)(ur & 0xffffu);
            slotD = offD[d] + (int)(ur >> 16);
        } else {
            s = d = e - E;
            slotS = offS[s + 1] - 1;
            slotD = offD[d + 1] - 1;
        }
        bool doS = (s >= lo) & (s < hi);
        bool doD = (d >= lo) & (d < hi);
        if (doS | doD) {
            int nb = __float_as_int(norm[e]);
            if (doS) csrS[slotS] = make_int2(d, nb);
            if (doD) csrD[slotD] = make_int2(s, nb);
        }
    }
}

// ---------------- softmax stats by src: 32 lanes/node, outputs node scalars ----------------
// sinfoA[node] = {ds, dssw, mA, sA}; sinfoB[node] = {mN, sN}; both replicated x8.
__global__ __launch_bounds__(256) void k_soft(const int* __restrict__ offS,
                                              const int2* __restrict__ csrS,
                                              const float* __restrict__ ds,
                                              const float* __restrict__ dssw,
                                              const float2* __restrict__ dtp,
                                              const float* __restrict__ ab,
                                              const float* __restrict__ sb,
                                              float4* __restrict__ sinfoA,
                                              float2* __restrict__ sinfoB,
                                              int n) {
    const float2* dtpc = dtp + (size_t)(blockIdx.x & 7) * n;
    int node = blockIdx.x * 8 + (threadIdx.x >> 5);
    int lane = threadIdx.x & 31;
    if (node >= n) return;
    int beg = offS[node];
    int deg = offS[node + 1] - beg;
    float ds_s = ds[node], dssw_s = dssw[node];
    float ab0 = ab[0], sb0 = sb[0];
    float mAv, mNv, sAv, sNv;

    if (deg <= 32) {
        bool valid = lane < deg;
        float sim = -INFINITY, nsim = -INFINITY;
        if (valid) {
            int2 c = csrS[beg + lane];
            float nr = __int_as_float(c.y);
            float2 p = dtpc[c.x];
            sim = lrelu(nr * (ds_s + p.x) + ab0);
            nsim = lrelu(dssw_s + p.y + sb0);
        }
        mAv = wmax32(sim);
        mNv = wmax32(nsim);
        sAv = wsum32(valid ? expf(sim - mAv) : 0.f);
        sNv = wsum32(valid ? expf(nsim - mNv) : 0.f);
    } else {
        mAv = -INFINITY; mNv = -INFINITY;
        for (int base = 0; base < deg; base += 32) {
            int idx = base + lane;
            if (idx < deg) {
                int2 c = csrS[beg + idx];
                float nr = __int_as_float(c.y);
                float2 p = dtpc[c.x];
                mAv = fmaxf(mAv, lrelu(nr * (ds_s + p.x) + ab0));
                mNv = fmaxf(mNv, lrelu(dssw_s + p.y + sb0));
            }
        }
        mAv = wmax32(mAv);
        mNv = wmax32(mNv);
        float a = 0.f, bb = 0.f;
        for (int base = 0; base < deg; base += 32) {
            int idx = base + lane;
            if (idx < deg) {
                int2 c = csrS[beg + idx];
                float nr = __int_as_float(c.y);
                float2 p = dtpc[c.x];
                a += expf(lrelu(nr * (ds_s + p.x) + ab0) - mAv);
                bb += expf(lrelu(dssw_s + p.y + sb0) - mNv);
            }
        }
        sAv = wsum32(a);
        sNv = wsum32(bb);
    }
    if (lane == 0) {
        float4 va = make_float4(ds_s, dssw_s, mAv, sAv);
        float2 vb = make_float2(mNv, sNv);
        for (int rep = 0; rep < 8; rep++) {
            sinfoA[(size_t)rep * n + node] = va;
            sinfoB[(size_t)rep * n + node] = vb;
        }
    }
}

// ---------------- aggregation by dst: wave per node, inline weight recompute ----------------
__global__ __launch_bounds__(256) void k_aggr(const int* __restrict__ offD,
                                              const int2* __restrict__ csrD,
                                              const float4* __restrict__ sinfoA,
                                              const float2* __restrict__ sinfoB,
                                              const float2* __restrict__ dtp,
                                              const __half* __restrict__ HhR,
                                              size_t hN, int R,
                                              const float* __restrict__ ab,
                                              const float* __restrict__ sb,
                                              const float* __restrict__ alpha,
                                              const float* __restrict__ bias,
                                              float* __restrict__ out, int n) {
    int cpy = blockIdx.x & 7;
    const float4* sA_ = sinfoA + (size_t)cpy * n;
    const float2* sB_ = sinfoB + (size_t)cpy * n;
    const float2* dt_ = dtp + (size_t)cpy * n;
    const __half* Hh = HhR + (size_t)(blockIdx.x & (R - 1)) * hN;
    int node = blockIdx.x * 4 + (threadIdx.x >> 6);
    int lane = threadIdx.x & 63;
    if (node >= n) return;
    int beg = offD[node];
    int deg = offD[node + 1] - beg;
    float2 dtd = dt_[node];
    float ab0 = ab[0], sb0 = sb[0], al = alpha[0];
    float m0 = -INFINITY, m1 = -INFINITY, m2 = -INFINITY, m3 = -INFINITY;
    float m4 = -INFINITY, m5 = -INFINITY, m6 = -INFINITY, m7 = -INFINITY;
    for (int base = 0; base < deg; base += 64) {
        int idx = base + lane;
        int s = 0;
        float wv = 0.f;
        if (idx < deg) {
            int2 c = csrD[beg + idx];
            s = c.x;
            float nr = __int_as_float(c.y);
            float4 ia = sA_[s];
            float2 ib = sB_[s];
            float sim = lrelu(nr * (ia.x + dtd.x) + ab0);
            float nsim = lrelu(ia.y + dtd.y + sb0);
            wv = al * expf(sim - ia.z) / ia.w
               + (1.f - al) * expf(nsim - ib.x) / ib.y;
        }
        int cnt = min(64, deg - base);
        int cnt8 = cnt & ~7;
        for (int j = 0; j < cnt8; j += 8) {
            int s0 = __shfl(s, j),     s1 = __shfl(s, j + 1),
                s2 = __shfl(s, j + 2), s3 = __shfl(s, j + 3),
                s4 = __shfl(s, j + 4), s5 = __shfl(s, j + 5),
                s6 = __shfl(s, j + 6), s7 = __shfl(s, j + 7);
            float w0 = __shfl(wv, j),     w1 = __shfl(wv, j + 1),
                  w2 = __shfl(wv, j + 2), w3 = __shfl(wv, j + 3),
                  w4 = __shfl(wv, j + 4), w5 = __shfl(wv, j + 5),
                  w6 = __shfl(wv, j + 6), w7 = __shfl(wv, j + 7);
            float h0 = __half2float(Hh[(size_t)s0 * HID + lane]);
            float h1 = __half2float(Hh[(size_t)s1 * HID + lane]);
            float h2 = __half2float(Hh[(size_t)s2 * HID + lane]);
            float h3 = __half2float(Hh[(size_t)s3 * HID + lane]);
            float h4 = __half2float(Hh[(size_t)s4 * HID + lane]);
            float h5 = __half2float(Hh[(size_t)s5 * HID + lane]);
            float h6 = __half2float(Hh[(size_t)s6 * HID + lane]);
            float h7 = __half2float(Hh[(size_t)s7 * HID + lane]);
            m0 = fmaxf(m0, w0 * h0); m1 = fmaxf(m1, w1 * h1);
            m2 = fmaxf(m2, w2 * h2); m3 = fmaxf(m3, w3 * h3);
            m4 = fmaxf(m4, w4 * h4); m5 = fmaxf(m5, w5 * h5);
            m6 = fmaxf(m6, w6 * h6); m7 = fmaxf(m7, w7 * h7);
        }
        for (int j = cnt8; j < cnt; j++) {
            int sj = __shfl(s, j);
            float wj = __shfl(wv, j);
            m0 = fmaxf(m0, wj * __half2float(Hh[(size_t)sj * HID + lane]));
        }
    }
    float m = fmaxf(fmaxf(fmaxf(m0, m1), fmaxf(m2, m3)),
                    fmaxf(fmaxf(m4, m5), fmaxf(m6, m7)));
    out[(size_t)node * HID + lane] = fmaxf(m + bias[lane], 0.f);
}

// ---------------- logits + log_softmax: 8 lanes/node, 5 classes/lane ----------------
__global__ __launch_bounds__(256) void k_logits(const float* __restrict__ H,
                                                const float* __restrict__ OW,
                                                const float* __restrict__ OB,
                                                float* __restrict__ out, int n) {
    __shared__ float Wl[CLS * HID];
    __shared__ float Bl[CLS];
    int tid = threadIdx.x;
    for (int i = tid; i < CLS * HID; i += 256) Wl[i] = OW[i];
    if (tid < CLS) Bl[tid] = OB[tid];
    __syncthreads();
    int node = blockIdx.x * 32 + (tid >> 3);
    int g = tid & 7;
    if (node >= n) return;
    const float* h = H + (size_t)node * HID;
    float hreg[HID];
#pragma unroll
    for (int k = 0; k < HID; k += 4) {
        float4 hv = *reinterpret_cast<const float4*>(h + k);
        hreg[k] = hv.x; hreg[k + 1] = hv.y; hreg[k + 2] = hv.z; hreg[k + 3] = hv.w;
    }
    float lg[5];
#pragma unroll
    for (int j = 0; j < 5; j++) {
        int c = g * 5 + j;
        float a = 0.f;
        const float* wr = &Wl[c * HID];
#pragma unroll
        for (int k = 0; k < HID; k++) a += hreg[k] * wr[k];
        lg[j] = a + Bl[c];
    }
    float m = lg[0];
#pragma unroll
    for (int j = 1; j < 5; j++) m = fmaxf(m, lg[j]);
    m = fmaxf(m, __shfl_xor(m, 1));
    m = fmaxf(m, __shfl_xor(m, 2));
    m = fmaxf(m, __shfl_xor(m, 4));
    float s = 0.f;
#pragma unroll
    for (int j = 0; j < 5; j++) s += expf(lg[j] - m);
    s += __shfl_xor(s, 1);
    s += __shfl_xor(s, 2);
    s += __shfl_xor(s, 4);
    float lse = m + logf(s);
    float* o = out + (size_t)node * CLS + g * 5;
#pragma unroll
    for (int j = 0; j < 5; j++) o[j] = lg[j] - lse;
}

extern "C" void kernel_launch(void* const* d_in, const int* in_sizes, int n_in,
                              void* d_out, int out_size, void* d_ws, size_t ws_size,
                              hipStream_t stream) {
    const float* x   = (const float*)d_in[0];
    const int*   ei  = (const int*)d_in[1];
    const float* nrm = (const float*)d_in[2];
    const float* w0  = (const float*)d_in[3];
    const float* w1  = (const float*)d_in[4];
    const float* aw0 = (const float*)d_in[5];
    const float* ab0 = (const float*)d_in[6];
    const float* aw1 = (const float*)d_in[7];
    const float* ab1 = (const float*)d_in[8];
    const float* sw0 = (const float*)d_in[9];
    const float* sb0 = (const float*)d_in[10];
    const float* sw1 = (const float*)d_in[11];
    const float* sb1 = (const float*)d_in[12];
    const float* al0 = (const float*)d_in[13];
    const float* al1 = (const float*)d_in[14];
    const float* b0  = (const float*)d_in[15];
    const float* b1  = (const float*)d_in[16];
    const float* ow  = (const float*)d_in[17];
    const float* ob  = (const float*)d_in[18];
    float* out = (float*)d_out;

    int N = in_sizes[0] / 128;
    int E = in_sizes[1] / 2;
    int Et = E + N;

    char* base = (char*)d_ws;
    size_t off = 0;
    auto alloc = [&](size_t bytes) {
        void* p = base + off;
        off += (bytes + 255) & ~(size_t)255;
        return p;
    };
    int* degS = (int*)alloc(N * 4);
    int* degD = (int*)alloc(N * 4);
    int* offS = (int*)alloc((N + 1) * 4);
    int* offD = (int*)alloc((N + 1) * 4);
    int* bsum = (int*)alloc(128 * 4);
    unsigned* ranks = (unsigned*)alloc((size_t)E * 4);
    int2* csrS = (int2*)alloc((size_t)Et * 8);
    int2* csrD = (int2*)alloc((size_t)Et * 8);
    float* ds    = (float*)alloc(N * 4);
    float* dssw  = (float*)alloc(N * 4);
    float* dtraw = (float*)alloc(N * 4);
    float* d2raw = (float*)alloc(N * 4);
    float* d3raw = (float*)alloc(N * 4);
    float2* dtp  = (float2*)alloc((size_t)N * 8 * 8);       // 8 copies
    float4* sinfoA = (float4*)alloc((size_t)N * 16 * 8);    // 8 copies
    float2* sinfoB = (float2*)alloc((size_t)N * 8 * 8);     // 8 copies
    float* lay   = (float*)alloc((size_t)N * HID * 4);

    // H replication factor: as many XCD-local copies as fit (power of 2, <=8)
    size_t hbytes = (size_t)N * HID * 2;
    size_t rem = (off < ws_size) ? ws_size - off : hbytes;
    int R = 1;
    while (R < 8 && (size_t)(R * 2) * hbytes <= rem) R <<= 1;
    __half* HhR = (__half*)alloc(hbytes * R);
    size_t hN = (size_t)N * HID;

    int nbN = (N + 255) / 256;
    int nbScan = (N + 1023) / 1024;
    int nbW = (N + 3) / 4;      // aggr: wave per node
    int nbS = (N + 7) / 8;      // soft: 2 nodes per wave
    int gb = (N + 63) / 64;     // gemm blocks (64 rows each)
    int cnb = (E + 1023) / 1024;

    k_deginit<<<nbN, 256, 0, stream>>>(degS, degD, N);
    k_fused0<<<gb + cnb, 256, 0, stream>>>(x, w0, aw0, sw0, HhR, hN, R, ds,
                                           dtraw, d2raw, d3raw,
                                           ei, degS, degD, ranks, N, E, gb);
    k_scanA<<<2 * nbScan, 1024, 0, stream>>>(degS, degD, d2raw, d3raw, dtraw,
                                             offS, offD, bsum, dssw, dtp,
                                             N, nbScan);
    k_scanB<<<1, 64, 0, stream>>>(bsum, nbScan);
    k_scanC<<<2 * nbScan, 1024, 0, stream>>>(degS, degD, offS, offD, bsum,
                                             N, Et, nbScan);
    k_scatter<<<2048, 256, 0, stream>>>(ei, nrm, offS, offD, ranks,
                                        csrS, csrD, Et, E, N);

    // layer 0
    k_soft<<<nbS, 256, 0, stream>>>(offS, csrS, ds, dssw, dtp,
                                    ab0, sb0, sinfoA, sinfoB, N);
    k_aggr<<<nbW, 256, 0, stream>>>(offD, csrD, sinfoA, sinfoB, dtp,
                                    HhR, hN, R, ab0, sb0, al0, b0, lay, N);

    // layer 1
    k_gemm1<<<gb, 256, 0, stream>>>(lay, w1, aw1, sw1, degS, degD,
                                    HhR, hN, R, ds, dssw, dtp, N);
    k_soft<<<nbS, 256, 0, stream>>>(offS, csrS, ds, dssw, dtp,
                                    ab1, sb1, sinfoA, sinfoB, N);
    k_aggr<<<nbW, 256, 0, stream>>>(offD, csrD, sinfoA, sinfoB, dtp,
                                    HhR, hN, R, ab1, sb1, al1, b1, lay, N);

    k_logits<<<(N + 31) / 32, 256, 0, stream>>>(lay, ow, ob, out, N);
}

// Round 9
// 293.978 us; speedup vs baseline: 1.2109x; 1.2109x over previous
//
#include <hip/hip_runtime.h>
#include <hip/hip_fp16.h>
#include <cstddef>

#define HID 64
#define CLS 40

__device__ __forceinline__ float lrelu(float x) { return x >= 0.f ? x : 0.2f * x; }

__device__ __forceinline__ float wmax32(float v) {
#pragma unroll
    for (int o = 16; o > 0; o >>= 1) v = fmaxf(v, __shfl_xor(v, o));
    return v;
}
__device__ __forceinline__ float wsum32(float v) {
#pragma unroll
    for (int o = 16; o > 0; o >>= 1) v += __shfl_xor(v, o);
    return v;
}

// ---------------- GEMM body: 64 rows/block, 4 threads/row ----------------
// W staged in LDS, row stride K+4, seg-interleaved columns (2-way conflict = free).
// Writes R replicated copies of the fp16 H row (one per XCD consumer).
template <int K, bool APPLY>
__device__ __forceinline__ void gemm_body(const float* __restrict__ X,
                                          const float* __restrict__ W,
                                          const float* __restrict__ aw,
                                          const float* __restrict__ sw,
                                          const int* __restrict__ degS,
                                          const int* __restrict__ degD,
                                          __half* __restrict__ Hh, size_t hN, int R,
                                          float* __restrict__ ds,
                                          float* __restrict__ dssw,
                                          float2* __restrict__ dtp,
                                          float* __restrict__ dtraw,
                                          float* __restrict__ d2raw,
                                          float* __restrict__ d3raw,
                                          int n, int brow, int tid) {
    constexpr int STR = K + 4;
    __shared__ float Wl[HID * STR];
    __shared__ float awl[128];
    __shared__ float swl[128];
    for (int i = tid; i < HID * K; i += 256) {
        int c = i / K, k = i % K;
        Wl[c * STR + k] = W[i];
    }
    if (tid < 128) awl[tid] = aw[tid];
    else swl[tid - 128] = sw[tid - 128];
    __syncthreads();
    int r = brow * 64 + (tid >> 2);
    int seg = tid & 3;
    if (r >= n) return;
    float acc[16];
#pragma unroll
    for (int c = 0; c < 16; c++) acc[c] = 0.f;
    const float* xr = X + (size_t)r * K;
    const float* wb = &Wl[4 * seg * STR];
    for (int k = 0; k < K; k += 4) {
        float4 xv = *reinterpret_cast<const float4*>(xr + k);
#pragma unroll
        for (int c = 0; c < 16; c++) {
            int crel = 16 * (c >> 2) + (c & 3);
            float4 wv = *reinterpret_cast<const float4*>(wb + crel * STR + k);
            acc[c] += xv.x * wv.x + xv.y * wv.y + xv.z * wv.z + xv.w * wv.w;
        }
    }
    float d0 = 0.f, d1 = 0.f, d2 = 0.f, d3 = 0.f;
#pragma unroll
    for (int c = 0; c < 16; c++) {
        int cc = 16 * (c >> 2) + 4 * seg + (c & 3);
        d0 += acc[c] * awl[cc];
        d1 += acc[c] * awl[64 + cc];
        d2 += acc[c] * swl[cc];
        d3 += acc[c] * swl[64 + cc];
    }
    uint2 stv[4];
#pragma unroll
    for (int t = 0; t < 4; t++) {
        union { __half2 h2[2]; uint2 u; } st;
        st.h2[0] = __floats2half2_rn(acc[4 * t], acc[4 * t + 1]);
        st.h2[1] = __floats2half2_rn(acc[4 * t + 2], acc[4 * t + 3]);
        stv[t] = st.u;
    }
    for (int rep = 0; rep < R; rep++) {
        __half* hb = Hh + (size_t)rep * hN + (size_t)r * HID + 4 * seg;
#pragma unroll
        for (int t = 0; t < 4; t++)
            *reinterpret_cast<uint2*>(hb + 16 * t) = stv[t];
    }
    // quad reduce (threads 4q..4q+3 share row r)
    d0 += __shfl_xor(d0, 1); d0 += __shfl_xor(d0, 2);
    d1 += __shfl_xor(d1, 1); d1 += __shfl_xor(d1, 2);
    d2 += __shfl_xor(d2, 1); d2 += __shfl_xor(d2, 2);
    d3 += __shfl_xor(d3, 1); d3 += __shfl_xor(d3, 2);
    if (seg == 0) {
        ds[r] = d0;
        if (APPLY) {
            dssw[r] = (float)(degS[r] + 1) * d2;
            float2 v = make_float2(d1, (float)(degD[r] + 1) * d3);
            for (int rep = 0; rep < 8; rep++) dtp[(size_t)rep * n + r] = v;
        } else {
            dtraw[r] = d1;
            d2raw[r] = d2;
            d3raw[r] = d3;
        }
    }
}

// ---------------- fused: layer-0 GEMM (independent) + degree count/rank ----------------
__global__ __launch_bounds__(256) void k_fused0(const float* __restrict__ x,
                                                const float* __restrict__ w0,
                                                const float* __restrict__ aw,
                                                const float* __restrict__ sw,
                                                __half* __restrict__ Hh, size_t hN, int R,
                                                float* __restrict__ ds,
                                                float* __restrict__ dtraw,
                                                float* __restrict__ d2raw,
                                                float* __restrict__ d3raw,
                                                const int* __restrict__ ei,
                                                int* degS, int* degD,
                                                unsigned* __restrict__ ranks,
                                                int n, int E, int gb) {
    if ((int)blockIdx.x < gb) {
        gemm_body<128, false>(x, w0, aw, sw, nullptr, nullptr, Hh, hN, R, ds,
                              nullptr, nullptr, dtraw, d2raw, d3raw,
                              n, blockIdx.x, threadIdx.x);
    } else {
        int t = (blockIdx.x - gb) * 256 + threadIdx.x;
        int stride = (gridDim.x - gb) * 256;
        for (int e = t; e < E; e += stride) {
            int s = ei[e], d = ei[E + e];
            unsigned rs = (unsigned)atomicAdd(&degS[s], 1);
            unsigned rd = (unsigned)atomicAdd(&degD[d], 1);
            ranks[e] = rs | (rd << 16);  // deg < 65536
        }
    }
}

// ---------------- layer-1 GEMM ----------------
__global__ __launch_bounds__(256) void k_gemm1(const float* __restrict__ X,
                                               const float* __restrict__ W,
                                               const float* __restrict__ aw,
                                               const float* __restrict__ sw,
                                               const int* __restrict__ degS,
                                               const int* __restrict__ degD,
                                               __half* __restrict__ Hh, size_t hN, int R,
                                               float* __restrict__ ds,
                                               float* __restrict__ dssw,
                                               float2* __restrict__ dtp,
                                               int n) {
    gemm_body<64, true>(X, W, aw, sw, degS, degD, Hh, hN, R, ds, dssw, dtp,
                        nullptr, nullptr, nullptr, n, blockIdx.x, threadIdx.x);
}

// ---------------- combined scans: S (blocks 0..nb-1) and D (nb..2nb-1) ----------------
__global__ __launch_bounds__(1024) void k_scanA(const int* __restrict__ degS,
                                                const int* __restrict__ degD,
                                                const float* __restrict__ d2raw,
                                                const float* __restrict__ d3raw,
                                                const float* __restrict__ dtraw,
                                                int* __restrict__ offS,
                                                int* __restrict__ offD,
                                                int* __restrict__ bsum,
                                                float* __restrict__ dssw,
                                                float2* __restrict__ dtp,
                                                int n, int nb) {
    __shared__ int buf[2][1024];
    int which = (int)blockIdx.x >= nb;
    const int* deg = which ? degD : degS;
    int* off = which ? offD : offS;
    int b = blockIdx.x - (which ? nb : 0);
    int tid = threadIdx.x;
    int i = b * 1024 + tid;
    int v = (i < n) ? deg[i] + 1 : 0;
    int cur = 0;
    buf[0][tid] = v;
    __syncthreads();
#pragma unroll
    for (int o = 1; o < 1024; o <<= 1) {
        int t = buf[cur][tid];
        if (tid >= o) t += buf[cur][tid - o];
        buf[cur ^ 1][tid] = t;
        cur ^= 1;
        __syncthreads();
    }
    if (i < n) off[i] = buf[cur][tid];
    if (tid == 1023) bsum[which * 64 + b] = buf[cur][1023];
    if (!which && i < n) {
        dssw[i] = (float)(degS[i] + 1) * d2raw[i];
        float2 vv = make_float2(dtraw[i], (float)(degD[i] + 1) * d3raw[i]);
        for (int rep = 0; rep < 8; rep++) dtp[(size_t)rep * n + i] = vv;
    }
}

// scanC with inlined block-sum prefix (replaces scanB+scanC)
__global__ __launch_bounds__(1024) void k_scanC(const int* __restrict__ degS,
                                                const int* __restrict__ degD,
                                                int* __restrict__ offS,
                                                int* __restrict__ offD,
                                                const int* __restrict__ bsum,
                                                int n, int total, int nb) {
    __shared__ int basesum;
    int which = (int)blockIdx.x >= nb;
    const int* deg = which ? degD : degS;
    int* off = which ? offD : offS;
    int b = blockIdx.x - (which ? nb : 0);
    if (threadIdx.x < 64) {
        int v = ((int)threadIdx.x < b) ? bsum[which * 64 + threadIdx.x] : 0;
#pragma unroll
        for (int o = 32; o > 0; o >>= 1) v += __shfl_xor(v, o);
        if (threadIdx.x == 0) basesum = v;
    }
    __syncthreads();
    int i = b * 1024 + threadIdx.x;
    if (i < n) off[i] = off[i] - (deg[i] + 1) + basesum;
    if (i == 0) off[n] = total;
}

// ---------------- slots pre-pass: slot = off[node] + rank, computed ONCE ----------------
__global__ __launch_bounds__(256) void k_slots(const int* __restrict__ ei,
                                               const unsigned* __restrict__ ranks,
                                               const int* __restrict__ offS,
                                               const int* __restrict__ offD,
                                               int2* __restrict__ slots,
                                               int Et, int E) {
    int e = blockIdx.x * 256 + threadIdx.x;
    if (e >= Et) return;
    if (e < E) {
        int s = ei[e], d = ei[E + e];
        unsigned ur = ranks[e];
        slots[e] = make_int2(offS[s] + (int)(ur & 0xffffu),
                             offD[d] + (int)(ur >> 16));
    } else {
        int v = e - E;  // self-loop: LAST slot of each segment
        slots[e] = make_int2(offS[v + 1] - 1, offD[v + 1] - 1);
    }
}

// ---------------- scatter: XCD-partitioned via slot-range test ----------------
// csrS[slotS] = {dst, norm_bits};  csrD[slotD] = {src, slotS}
__global__ __launch_bounds__(256) void k_scatter(const int* __restrict__ ei,
                                                 const float* __restrict__ norm,
                                                 const int2* __restrict__ slots,
                                                 const int* __restrict__ offS,
                                                 const int* __restrict__ offD,
                                                 int2* __restrict__ csrS,
                                                 int2* __restrict__ csrD,
                                                 int Et, int E, int N) {
    int grp = blockIdx.x & 7;
    int lo = (int)(((long long)grp * N) / 8);
    int hi = (int)(((long long)(grp + 1) * N) / 8);
    int sLo = offS[lo], sHi = offS[hi];
    int dLo = offD[lo], dHi = offD[hi];
    int start = (blockIdx.x >> 3) * 256 + threadIdx.x;
    int stride = (gridDim.x >> 3) * 256;
    for (int e = start; e < Et; e += stride) {
        int2 sl = slots[e];
        bool doS = (sl.x >= sLo) & (sl.x < sHi);
        bool doD = (sl.y >= dLo) & (sl.y < dHi);
        if (doS | doD) {
            int nb = __float_as_int(norm[e]);
            if (doS) {
                int d = (e < E) ? ei[E + e] : e - E;
                csrS[sl.x] = make_int2(d, nb);
            }
            if (doD) {
                int s = (e < E) ? ei[e] : e - E;
                csrD[sl.y] = make_int2(s, sl.x);
            }
        }
    }
}

// ---------------- softmax by src: 32 lanes/node, writes per-edge weight ----------------
__global__ __launch_bounds__(256) void k_soft(const int* __restrict__ offS,
                                              const int2* __restrict__ csrS,
                                              const float* __restrict__ ds,
                                              const float* __restrict__ dssw,
                                              const float2* __restrict__ dtp,
                                              const float* __restrict__ ab,
                                              const float* __restrict__ sb,
                                              const float* __restrict__ alpha,
                                              float* __restrict__ w, int n) {
    const float2* dtpc = dtp + (size_t)(blockIdx.x & 7) * n;
    int node = blockIdx.x * 8 + (threadIdx.x >> 5);
    int lane = threadIdx.x & 31;
    if (node >= n) return;
    int beg = offS[node];
    int deg = offS[node + 1] - beg;
    float ds_s = ds[node], dssw_s = dssw[node];
    float ab0 = ab[0], sb0 = sb[0], al = alpha[0];

    if (deg <= 32) {
        bool valid = lane < deg;
        float sim = -INFINITY, nsim = -INFINITY;
        int pos = beg + lane;
        if (valid) {
            int2 c = csrS[pos];
            float nr = __int_as_float(c.y);
            float2 p = dtpc[c.x];
            sim = lrelu(nr * (ds_s + p.x) + ab0);
            nsim = lrelu(dssw_s + p.y + sb0);
        }
        float mAv = wmax32(sim), mNv = wmax32(nsim);
        float eA = valid ? expf(sim - mAv) : 0.f;
        float eN = valid ? expf(nsim - mNv) : 0.f;
        float sAv = wsum32(eA), sNv = wsum32(eN);
        if (valid) w[pos] = al * eA / sAv + (1.f - al) * eN / sNv;
    } else {
        float mAv = -INFINITY, mNv = -INFINITY;
        for (int base = 0; base < deg; base += 32) {
            int idx = base + lane;
            if (idx < deg) {
                int2 c = csrS[beg + idx];
                float nr = __int_as_float(c.y);
                float2 p = dtpc[c.x];
                mAv = fmaxf(mAv, lrelu(nr * (ds_s + p.x) + ab0));
                mNv = fmaxf(mNv, lrelu(dssw_s + p.y + sb0));
            }
        }
        mAv = wmax32(mAv);
        mNv = wmax32(mNv);
        float a = 0.f, bb = 0.f;
        for (int base = 0; base < deg; base += 32) {
            int idx = base + lane;
            if (idx < deg) {
                int2 c = csrS[beg + idx];
                float nr = __int_as_float(c.y);
                float2 p = dtpc[c.x];
                a += expf(lrelu(nr * (ds_s + p.x) + ab0) - mAv);
                bb += expf(lrelu(dssw_s + p.y + sb0) - mNv);
            }
        }
        float sAv = wsum32(a);
        float sNv = wsum32(bb);
        for (int base = 0; base < deg; base += 32) {
            int idx = base + lane;
            if (idx < deg) {
                int2 c = csrS[beg + idx];
                float nr = __int_as_float(c.y);
                float2 p = dtpc[c.x];
                float eA = expf(lrelu(nr * (ds_s + p.x) + ab0) - mAv);
                float eN = expf(lrelu(dssw_s + p.y + sb0) - mNv);
                w[beg + idx] = al * eA / sAv + (1.f - al) * eN / sNv;
            }
        }
    }
}

// ---------------- aggregation by dst: 32 lanes/node, 2 nodes/wave ----------------
// Each lane covers HID entries {l32, l32+32} of its half's node.
__global__ __launch_bounds__(256) void k_aggr(const int* __restrict__ offD,
                                              const int2* __restrict__ csrD,
                                              const float* __restrict__ w,
                                              const __half* __restrict__ HhR,
                                              size_t hN, int R,
                                              const float* __restrict__ bias,
                                              float* __restrict__ out, int n) {
    const __half* Hh = HhR + (size_t)(blockIdx.x & (R - 1)) * hN;
    int wid = threadIdx.x >> 6;
    int lane = threadIdx.x & 63;
    int half = lane >> 5;
    int l32 = lane & 31;
    int node = (blockIdx.x * 4 + wid) * 2 + half;
    bool nvalid = node < n;
    int beg = 0, deg = 0;
    if (nvalid) { beg = offD[node]; deg = offD[node + 1] - beg; }
    int degOther = __shfl(deg, lane ^ 32);
    int maxdeg = max(deg, degOther);
    float ml0 = -INFINITY, ml1 = -INFINITY, ml2 = -INFINITY, ml3 = -INFINITY;
    float mh0 = -INFINITY, mh1 = -INFINITY, mh2 = -INFINITY, mh3 = -INFINITY;
    for (int base = 0; base < maxdeg; base += 32) {
        int idx = base + l32;
        int s = 0;
        float wv = 0.f;
        if (idx < deg) {
            int2 c = csrD[beg + idx];
            s = c.x;
            wv = w[c.y];
        }
        int cnt = min(32, maxdeg - base);
        int cnt4 = cnt & ~3;
        int bl = half << 5;
        for (int j = 0; j < cnt4; j += 4) {
            int s0 = __shfl(s, bl + j),     s1 = __shfl(s, bl + j + 1),
                s2 = __shfl(s, bl + j + 2), s3 = __shfl(s, bl + j + 3);
            float w0 = __shfl(wv, bl + j),     w1 = __shfl(wv, bl + j + 1),
                  w2 = __shfl(wv, bl + j + 2), w3 = __shfl(wv, bl + j + 3);
            float hl0 = __half2float(Hh[(size_t)s0 * HID + l32]);
            float hh0 = __half2float(Hh[(size_t)s0 * HID + 32 + l32]);
            float hl1 = __half2float(Hh[(size_t)s1 * HID + l32]);
            float hh1 = __half2float(Hh[(size_t)s1 * HID + 32 + l32]);
            float hl2 = __half2float(Hh[(size_t)s2 * HID + l32]);
            float hh2 = __half2float(Hh[(size_t)s2 * HID + 32 + l32]);
            float hl3 = __half2float(Hh[(size_t)s3 * HID + l32]);
            float hh3 = __half2float(Hh[(size_t)s3 * HID + 32 + l32]);
            if (base + j < deg)     { ml0 = fmaxf(ml0, w0 * hl0); mh0 = fmaxf(mh0, w0 * hh0); }
            if (base + j + 1 < deg) { ml1 = fmaxf(ml1, w1 * hl1); mh1 = fmaxf(mh1, w1 * hh1); }
            if (base + j + 2 < deg) { ml2 = fmaxf(ml2, w2 * hl2); mh2 = fmaxf(mh2, w2 * hh2); }
            if (base + j + 3 < deg) { ml3 = fmaxf(ml3, w3 * hl3); mh3 = fmaxf(mh3, w3 * hh3); }
        }
        for (int j = cnt4; j < cnt; j++) {
            int sj = __shfl(s, bl + j);
            float wj = __shfl(wv, bl + j);
            float hl = __half2float(Hh[(size_t)sj * HID + l32]);
            float hh = __half2float(Hh[(size_t)sj * HID + 32 + l32]);
            if (base + j < deg) { ml0 = fmaxf(ml0, wj * hl); mh0 = fmaxf(mh0, wj * hh); }
        }
    }
    if (nvalid) {
        float mlo = fmaxf(fmaxf(ml0, ml1), fmaxf(ml2, ml3));
        float mhi = fmaxf(fmaxf(mh0, mh1), fmaxf(mh2, mh3));
        out[(size_t)node * HID + l32] = fmaxf(mlo + bias[l32], 0.f);
        out[(size_t)node * HID + 32 + l32] = fmaxf(mhi + bias[32 + l32], 0.f);
    }
}

// ---------------- logits + log_softmax: 8 lanes/node, 5 classes/lane ----------------
__global__ __launch_bounds__(256) void k_logits(const float* __restrict__ H,
                                                const float* __restrict__ OW,
                                                const float* __restrict__ OB,
                                                float* __restrict__ out, int n) {
    __shared__ float Wl[CLS * HID];
    __shared__ float Bl[CLS];
    int tid = threadIdx.x;
    for (int i = tid; i < CLS * HID; i += 256) Wl[i] = OW[i];
    if (tid < CLS) Bl[tid] = OB[tid];
    __syncthreads();
    int node = blockIdx.x * 32 + (tid >> 3);
    int g = tid & 7;
    if (node >= n) return;
    const float* h = H + (size_t)node * HID;
    float hreg[HID];
#pragma unroll
    for (int k = 0; k < HID; k += 4) {
        float4 hv = *reinterpret_cast<const float4*>(h + k);
        hreg[k] = hv.x; hreg[k + 1] = hv.y; hreg[k + 2] = hv.z; hreg[k + 3] = hv.w;
    }
    float lg[5];
#pragma unroll
    for (int j = 0; j < 5; j++) {
        int c = g * 5 + j;
        float a = 0.f;
        const float* wr = &Wl[c * HID];
#pragma unroll
        for (int k = 0; k < HID; k++) a += hreg[k] * wr[k];
        lg[j] = a + Bl[c];
    }
    float m = lg[0];
#pragma unroll
    for (int j = 1; j < 5; j++) m = fmaxf(m, lg[j]);
    m = fmaxf(m, __shfl_xor(m, 1));
    m = fmaxf(m, __shfl_xor(m, 2));
    m = fmaxf(m, __shfl_xor(m, 4));
    float s = 0.f;
#pragma unroll
    for (int j = 0; j < 5; j++) s += expf(lg[j] - m);
    s += __shfl_xor(s, 1);
    s += __shfl_xor(s, 2);
    s += __shfl_xor(s, 4);
    float lse = m + logf(s);
    float* o = out + (size_t)node * CLS + g * 5;
#pragma unroll
    for (int j = 0; j < 5; j++) o[j] = lg[j] - lse;
}

extern "C" void kernel_launch(void* const* d_in, const int* in_sizes, int n_in,
                              void* d_out, int out_size, void* d_ws, size_t ws_size,
                              hipStream_t stream) {
    const float* x   = (const float*)d_in[0];
    const int*   ei  = (const int*)d_in[1];
    const float* nrm = (const float*)d_in[2];
    const float* w0  = (const float*)d_in[3];
    const float* w1  = (const float*)d_in[4];
    const float* aw0 = (const float*)d_in[5];
    const float* ab0 = (const float*)d_in[6];
    const float* aw1 = (const float*)d_in[7];
    const float* ab1 = (const float*)d_in[8];
    const float* sw0 = (const float*)d_in[9];
    const float* sb0 = (const float*)d_in[10];
    const float* sw1 = (const float*)d_in[11];
    const float* sb1 = (const float*)d_in[12];
    const float* al0 = (const float*)d_in[13];
    const float* al1 = (const float*)d_in[14];
    const float* b0  = (const float*)d_in[15];
    const float* b1  = (const float*)d_in[16];
    const float* ow  = (const float*)d_in[17];
    const float* ob  = (const float*)d_in[18];
    float* out = (float*)d_out;

    int N = in_sizes[0] / 128;
    int E = in_sizes[1] / 2;
    int Et = E + N;

    char* base = (char*)d_ws;
    size_t off = 0;
    auto alloc = [&](size_t bytes) {
        void* p = base + off;
        off += (bytes + 255) & ~(size_t)255;
        return p;
    };
    int* degS = (int*)alloc(N * 4);
    int* degD = (int*)alloc(N * 4);
    int* offS = (int*)alloc((N + 1) * 4);
    int* offD = (int*)alloc((N + 1) * 4);
    int* bsum = (int*)alloc(128 * 4);
    unsigned* ranks = (unsigned*)alloc((size_t)E * 4);
    int2* slots = (int2*)alloc((size_t)Et * 8);
    int2* csrS = (int2*)alloc((size_t)Et * 8);
    int2* csrD = (int2*)alloc((size_t)Et * 8);
    float* wgt   = (float*)alloc((size_t)Et * 4);
    float* ds    = (float*)alloc(N * 4);
    float* dssw  = (float*)alloc(N * 4);
    float* dtraw = (float*)alloc(N * 4);
    float* d2raw = (float*)alloc(N * 4);
    float* d3raw = (float*)alloc(N * 4);
    float2* dtp  = (float2*)alloc((size_t)N * 8 * 8);   // 8 XCD-local copies
    float* lay   = (float*)alloc((size_t)N * HID * 4);

    // H replication factor: as many XCD-local copies as fit (power of 2, <=8)
    size_t hbytes = (size_t)N * HID * 2;
    size_t rem = (off < ws_size) ? ws_size - off : hbytes;
    int R = 1;
    while (R < 8 && (size_t)(R * 2) * hbytes <= rem) R <<= 1;
    __half* HhR = (__half*)alloc(hbytes * R);
    size_t hN = (size_t)N * HID;

    int nbScan = (N + 1023) / 1024;
    int nbW2 = (N + 7) / 8;     // aggr: 2 nodes/wave, 4 waves/block
    int nbS = (N + 7) / 8;      // soft: 2 nodes/wave (32 lanes each)
    int gb = (N + 63) / 64;     // gemm blocks (64 rows each)
    int cnb = (E + 1023) / 1024;

    hipMemsetAsync(degS, 0, (size_t)N * 4, stream);
    hipMemsetAsync(degD, 0, (size_t)N * 4, stream);
    k_fused0<<<gb + cnb, 256, 0, stream>>>(x, w0, aw0, sw0, HhR, hN, R, ds,
                                           dtraw, d2raw, d3raw,
                                           ei, degS, degD, ranks, N, E, gb);
    k_scanA<<<2 * nbScan, 1024, 0, stream>>>(degS, degD, d2raw, d3raw, dtraw,
                                             offS, offD, bsum, dssw, dtp,
                                             N, nbScan);
    k_scanC<<<2 * nbScan, 1024, 0, stream>>>(degS, degD, offS, offD, bsum,
                                             N, Et, nbScan);
    k_slots<<<(Et + 255) / 256, 256, 0, stream>>>(ei, ranks, offS, offD,
                                                  slots, Et, E);
    k_scatter<<<2048, 256, 0, stream>>>(ei, nrm, slots, offS, offD,
                                        csrS, csrD, Et, E, N);

    // layer 0
    k_soft<<<nbS, 256, 0, stream>>>(offS, csrS, ds, dssw, dtp,
                                    ab0, sb0, al0, wgt, N);
    k_aggr<<<nbW2, 256, 0, stream>>>(offD, csrD, wgt, HhR, hN, R, b0, lay, N);

    // layer 1
    k_gemm1<<<gb, 256, 0, stream>>>(lay, w1, aw1, sw1, degS, degD,
                                    HhR, hN, R, ds, dssw, dtp, N);
    k_soft<<<nbS, 256, 0, stream>>>(offS, csrS, ds, dssw, dtp,
                                    ab1, sb1, al1, wgt, N);
    k_aggr<<<nbW2, 256, 0, stream>>>(offD, csrD, wgt, HhR, hN, R, b1, lay, N);

    k_logits<<<(N + 31) / 32, 256, 0, stream>>>(lay, ow, ob, out, N);
}

// Round 10
// 262.846 us; speedup vs baseline: 1.3543x; 1.1184x over previous
//
#include <hip/hip_runtime.h>
#include <hip/hip_fp16.h>
#include <cstddef>

#define HID 64
#define CLS 40

__device__ __forceinline__ float lrelu(float x) { return x >= 0.f ? x : 0.2f * x; }

__device__ __forceinline__ float wmax32(float v) {
#pragma unroll
    for (int o = 16; o > 0; o >>= 1) v = fmaxf(v, __shfl_xor(v, o));
    return v;
}
__device__ __forceinline__ float wsum32(float v) {
#pragma unroll
    for (int o = 16; o > 0; o >>= 1) v += __shfl_xor(v, o);
    return v;
}

// ---------------- GEMM body: 64 rows/block, 4 threads/row ----------------
// W staged in LDS, row stride K+4, seg-interleaved columns (2-way conflict = free).
// X dtype templated (fp32 layer 0, fp16 layer 1). Writes R replicated fp16 H copies.
template <int K, bool APPLY, typename XT>
__device__ __forceinline__ void gemm_body(const XT* __restrict__ X,
                                          const float* __restrict__ W,
                                          const float* __restrict__ aw,
                                          const float* __restrict__ sw,
                                          const int* __restrict__ degS,
                                          const int* __restrict__ degD,
                                          __half* __restrict__ Hh, size_t hN, int R,
                                          float* __restrict__ ds,
                                          float* __restrict__ dssw,
                                          float2* __restrict__ dtp,
                                          float* __restrict__ dtraw,
                                          float* __restrict__ d2raw,
                                          float* __restrict__ d3raw,
                                          int n, int brow, int tid) {
    constexpr int STR = K + 4;
    __shared__ float Wl[HID * STR];
    __shared__ float awl[128];
    __shared__ float swl[128];
    for (int i = tid; i < HID * K; i += 256) {
        int c = i / K, k = i % K;
        Wl[c * STR + k] = W[i];
    }
    if (tid < 128) awl[tid] = aw[tid];
    else swl[tid - 128] = sw[tid - 128];
    __syncthreads();
    int r = brow * 64 + (tid >> 2);
    int seg = tid & 3;
    if (r >= n) return;
    float acc[16];
#pragma unroll
    for (int c = 0; c < 16; c++) acc[c] = 0.f;
    const XT* xr = X + (size_t)r * K;
    const float* wb = &Wl[4 * seg * STR];
    for (int k = 0; k < K; k += 4) {
        float4 xv;
        if constexpr (sizeof(XT) == 4) {
            xv = *reinterpret_cast<const float4*>(xr + k);
        } else {
            __half2 a = *reinterpret_cast<const __half2*>(xr + k);
            __half2 b = *reinterpret_cast<const __half2*>(xr + k + 2);
            xv = make_float4(__low2float(a), __high2float(a),
                             __low2float(b), __high2float(b));
        }
#pragma unroll
        for (int c = 0; c < 16; c++) {
            int crel = 16 * (c >> 2) + (c & 3);
            float4 wv = *reinterpret_cast<const float4*>(wb + crel * STR + k);
            acc[c] += xv.x * wv.x + xv.y * wv.y + xv.z * wv.z + xv.w * wv.w;
        }
    }
    float d0 = 0.f, d1 = 0.f, d2 = 0.f, d3 = 0.f;
#pragma unroll
    for (int c = 0; c < 16; c++) {
        int cc = 16 * (c >> 2) + 4 * seg + (c & 3);
        d0 += acc[c] * awl[cc];
        d1 += acc[c] * awl[64 + cc];
        d2 += acc[c] * swl[cc];
        d3 += acc[c] * swl[64 + cc];
    }
    uint2 stv[4];
#pragma unroll
    for (int t = 0; t < 4; t++) {
        union { __half2 h2[2]; uint2 u; } st;
        st.h2[0] = __floats2half2_rn(acc[4 * t], acc[4 * t + 1]);
        st.h2[1] = __floats2half2_rn(acc[4 * t + 2], acc[4 * t + 3]);
        stv[t] = st.u;
    }
    for (int rep = 0; rep < R; rep++) {
        __half* hb = Hh + (size_t)rep * hN + (size_t)r * HID + 4 * seg;
#pragma unroll
        for (int t = 0; t < 4; t++)
            *reinterpret_cast<uint2*>(hb + 16 * t) = stv[t];
    }
    // quad reduce (threads 4q..4q+3 share row r)
    d0 += __shfl_xor(d0, 1); d0 += __shfl_xor(d0, 2);
    d1 += __shfl_xor(d1, 1); d1 += __shfl_xor(d1, 2);
    d2 += __shfl_xor(d2, 1); d2 += __shfl_xor(d2, 2);
    d3 += __shfl_xor(d3, 1); d3 += __shfl_xor(d3, 2);
    if (seg == 0) {
        ds[r] = d0;
        if (APPLY) {
            dssw[r] = (float)(degS[r] + 1) * d2;
            float2 v = make_float2(d1, (float)(degD[r] + 1) * d3);
            for (int rep = 0; rep < 8; rep++) dtp[(size_t)rep * n + r] = v;
        } else {
            dtraw[r] = d1;
            d2raw[r] = d2;
            d3raw[r] = d3;
        }
    }
}

// ---------------- fused: layer-0 GEMM (independent) + degree count/rank ----------------
__global__ __launch_bounds__(256) void k_fused0(const float* __restrict__ x,
                                                const float* __restrict__ w0,
                                                const float* __restrict__ aw,
                                                const float* __restrict__ sw,
                                                __half* __restrict__ Hh, size_t hN, int R,
                                                float* __restrict__ ds,
                                                float* __restrict__ dtraw,
                                                float* __restrict__ d2raw,
                                                float* __restrict__ d3raw,
                                                const int* __restrict__ ei,
                                                int* degS, int* degD,
                                                unsigned* __restrict__ ranks,
                                                int n, int E, int gb) {
    if ((int)blockIdx.x < gb) {
        gemm_body<128, false, float>(x, w0, aw, sw, nullptr, nullptr, Hh, hN, R, ds,
                                     nullptr, nullptr, dtraw, d2raw, d3raw,
                                     n, blockIdx.x, threadIdx.x);
    } else {
        int t = (blockIdx.x - gb) * 256 + threadIdx.x;
        int stride = (gridDim.x - gb) * 256;
        for (int e = t; e < E; e += stride) {
            int s = ei[e], d = ei[E + e];
            unsigned rs = (unsigned)atomicAdd(&degS[s], 1);
            unsigned rd = (unsigned)atomicAdd(&degD[d], 1);
            ranks[e] = rs | (rd << 16);  // deg < 65536
        }
    }
}

// ---------------- layer-1 GEMM (fp16 input) ----------------
__global__ __launch_bounds__(256) void k_gemm1(const __half* __restrict__ X,
                                               const float* __restrict__ W,
                                               const float* __restrict__ aw,
                                               const float* __restrict__ sw,
                                               const int* __restrict__ degS,
                                               const int* __restrict__ degD,
                                               __half* __restrict__ Hh, size_t hN, int R,
                                               float* __restrict__ ds,
                                               float* __restrict__ dssw,
                                               float2* __restrict__ dtp,
                                               int n) {
    gemm_body<64, true, __half>(X, W, aw, sw, degS, degD, Hh, hN, R, ds, dssw, dtp,
                                nullptr, nullptr, nullptr, n, blockIdx.x, threadIdx.x);
}

// ---------------- combined scans: S (blocks 0..nb-1) and D (nb..2nb-1) ----------------
__global__ __launch_bounds__(1024) void k_scanA(const int* __restrict__ degS,
                                                const int* __restrict__ degD,
                                                const float* __restrict__ d2raw,
                                                const float* __restrict__ d3raw,
                                                const float* __restrict__ dtraw,
                                                int* __restrict__ offS,
                                                int* __restrict__ offD,
                                                int* __restrict__ bsum,
                                                float* __restrict__ dssw,
                                                float2* __restrict__ dtp,
                                                int n, int nb) {
    __shared__ int buf[2][1024];
    int which = (int)blockIdx.x >= nb;
    const int* deg = which ? degD : degS;
    int* off = which ? offD : offS;
    int b = blockIdx.x - (which ? nb : 0);
    int tid = threadIdx.x;
    int i = b * 1024 + tid;
    int v = (i < n) ? deg[i] + 1 : 0;
    int cur = 0;
    buf[0][tid] = v;
    __syncthreads();
#pragma unroll
    for (int o = 1; o < 1024; o <<= 1) {
        int t = buf[cur][tid];
        if (tid >= o) t += buf[cur][tid - o];
        buf[cur ^ 1][tid] = t;
        cur ^= 1;
        __syncthreads();
    }
    if (i < n) off[i] = buf[cur][tid];
    if (tid == 1023) bsum[which * 64 + b] = buf[cur][1023];
    if (!which && i < n) {
        dssw[i] = (float)(degS[i] + 1) * d2raw[i];
        float2 vv = make_float2(dtraw[i], (float)(degD[i] + 1) * d3raw[i]);
        for (int rep = 0; rep < 8; rep++) dtp[(size_t)rep * n + i] = vv;
    }
}

// scanC with inlined block-sum prefix
__global__ __launch_bounds__(1024) void k_scanC(const int* __restrict__ degS,
                                                const int* __restrict__ degD,
                                                int* __restrict__ offS,
                                                int* __restrict__ offD,
                                                const int* __restrict__ bsum,
                                                int n, int total, int nb) {
    __shared__ int basesum;
    int which = (int)blockIdx.x >= nb;
    const int* deg = which ? degD : degS;
    int* off = which ? offD : offS;
    int b = blockIdx.x - (which ? nb : 0);
    if (threadIdx.x < 64) {
        int v = ((int)threadIdx.x < b) ? bsum[which * 64 + threadIdx.x] : 0;
#pragma unroll
        for (int o = 32; o > 0; o >>= 1) v += __shfl_xor(v, o);
        if (threadIdx.x == 0) basesum = v;
    }
    __syncthreads();
    int i = b * 1024 + threadIdx.x;
    if (i < n) off[i] = off[i] - (deg[i] + 1) + basesum;
    if (i == 0) off[n] = total;
}

// ---------------- slots pre-pass: slot = off[node] + rank, computed ONCE ----------------
__global__ __launch_bounds__(256) void k_slots(const int* __restrict__ ei,
                                               const unsigned* __restrict__ ranks,
                                               const int* __restrict__ offS,
                                               const int* __restrict__ offD,
                                               int2* __restrict__ slots,
                                               int Et, int E) {
    int e = blockIdx.x * 256 + threadIdx.x;
    if (e >= Et) return;
    if (e < E) {
        int s = ei[e], d = ei[E + e];
        unsigned ur = ranks[e];
        slots[e] = make_int2(offS[s] + (int)(ur & 0xffffu),
                             offD[d] + (int)(ur >> 16));
    } else {
        int v = e - E;  // self-loop: LAST slot of each segment
        slots[e] = make_int2(offS[v + 1] - 1, offD[v + 1] - 1);
    }
}

// ---------------- scatter: XCD-partitioned via slot-range test ----------------
// csrS[slotS] = {dst, norm_bits};  csrD[slotD] = {src, slotS}
__global__ __launch_bounds__(256) void k_scatter(const int* __restrict__ ei,
                                                 const float* __restrict__ norm,
                                                 const int2* __restrict__ slots,
                                                 const int* __restrict__ offS,
                                                 const int* __restrict__ offD,
                                                 int2* __restrict__ csrS,
                                                 int2* __restrict__ csrD,
                                                 int Et, int E, int N) {
    int grp = blockIdx.x & 7;
    int lo = (int)(((long long)grp * N) / 8);
    int hi = (int)(((long long)(grp + 1) * N) / 8);
    int sLo = offS[lo], sHi = offS[hi];
    int dLo = offD[lo], dHi = offD[hi];
    int start = (blockIdx.x >> 3) * 256 + threadIdx.x;
    int stride = (gridDim.x >> 3) * 256;
    for (int e = start; e < Et; e += stride) {
        int2 sl = slots[e];
        bool doS = (sl.x >= sLo) & (sl.x < sHi);
        bool doD = (sl.y >= dLo) & (sl.y < dHi);
        if (doS | doD) {
            int nb = __float_as_int(norm[e]);
            if (doS) {
                int d = (e < E) ? ei[E + e] : e - E;
                csrS[sl.x] = make_int2(d, nb);
            }
            if (doD) {
                int s = (e < E) ? ei[e] : e - E;
                csrD[sl.y] = make_int2(s, sl.x);
            }
        }
    }
}

// ---------------- softmax by src: 32 lanes/node, writes R fp16 weight copies ----------------
__global__ __launch_bounds__(256) void k_soft(const int* __restrict__ offS,
                                              const int2* __restrict__ csrS,
                                              const float* __restrict__ ds,
                                              const float* __restrict__ dssw,
                                              const float2* __restrict__ dtp,
                                              const float* __restrict__ ab,
                                              const float* __restrict__ sb,
                                              const float* __restrict__ alpha,
                                              __half* __restrict__ wgtR, int wN, int R,
                                              int n) {
    const float2* dtpc = dtp + (size_t)(blockIdx.x & 7) * n;
    int node = blockIdx.x * 8 + (threadIdx.x >> 5);
    int lane = threadIdx.x & 31;
    if (node >= n) return;
    int beg = offS[node];
    int deg = offS[node + 1] - beg;
    float ds_s = ds[node], dssw_s = dssw[node];
    float ab0 = ab[0], sb0 = sb[0], al = alpha[0];

    if (deg <= 32) {
        bool valid = lane < deg;
        float sim = -INFINITY, nsim = -INFINITY;
        int pos = beg + lane;
        if (valid) {
            int2 c = csrS[pos];
            float nr = __int_as_float(c.y);
            float2 p = dtpc[c.x];
            sim = lrelu(nr * (ds_s + p.x) + ab0);
            nsim = lrelu(dssw_s + p.y + sb0);
        }
        float mAv = wmax32(sim), mNv = wmax32(nsim);
        float eA = valid ? expf(sim - mAv) : 0.f;
        float eN = valid ? expf(nsim - mNv) : 0.f;
        float sAv = wsum32(eA), sNv = wsum32(eN);
        if (valid) {
            __half hv = __float2half(al * eA / sAv + (1.f - al) * eN / sNv);
            for (int rep = 0; rep < R; rep++) wgtR[(size_t)rep * wN + pos] = hv;
        }
    } else {
        float mAv = -INFINITY, mNv = -INFINITY;
        for (int base = 0; base < deg; base += 32) {
            int idx = base + lane;
            if (idx < deg) {
                int2 c = csrS[beg + idx];
                float nr = __int_as_float(c.y);
                float2 p = dtpc[c.x];
                mAv = fmaxf(mAv, lrelu(nr * (ds_s + p.x) + ab0));
                mNv = fmaxf(mNv, lrelu(dssw_s + p.y + sb0));
            }
        }
        mAv = wmax32(mAv);
        mNv = wmax32(mNv);
        float a = 0.f, bb = 0.f;
        for (int base = 0; base < deg; base += 32) {
            int idx = base + lane;
            if (idx < deg) {
                int2 c = csrS[beg + idx];
                float nr = __int_as_float(c.y);
                float2 p = dtpc[c.x];
                a += expf(lrelu(nr * (ds_s + p.x) + ab0) - mAv);
                bb += expf(lrelu(dssw_s + p.y + sb0) - mNv);
            }
        }
        float sAv = wsum32(a);
        float sNv = wsum32(bb);
        for (int base = 0; base < deg; base += 32) {
            int idx = base + lane;
            if (idx < deg) {
                int2 c = csrS[beg + idx];
                float nr = __int_as_float(c.y);
                float2 p = dtpc[c.x];
                float eA = expf(lrelu(nr * (ds_s + p.x) + ab0) - mAv);
                float eN = expf(lrelu(dssw_s + p.y + sb0) - mNv);
                __half hv = __float2half(al * eA / sAv + (1.f - al) * eN / sNv);
                for (int rep = 0; rep < R; rep++)
                    wgtR[(size_t)rep * wN + beg + idx] = hv;
            }
        }
    }
}

// ---------------- aggregation by dst: 32 lanes/node, 2 nodes/wave ----------------
// FINAL=false: write fp16 layer output. FINAL=true: fuse logits + log_softmax.
template <bool FINAL>
__global__ __launch_bounds__(256) void k_aggr(const int* __restrict__ offD,
                                              const int2* __restrict__ csrD,
                                              const __half* __restrict__ wgtR, int wN,
                                              const __half* __restrict__ HhR, size_t hN,
                                              int R,
                                              const float* __restrict__ bias,
                                              const float* __restrict__ OW,
                                              const float* __restrict__ OB,
                                              __half* __restrict__ outH,
                                              float* __restrict__ outF, int n) {
    __shared__ float WlT[FINAL ? HID * CLS : 1];  // transposed: WlT[k*CLS+c]
    __shared__ float Bl[FINAL ? CLS : 1];
    __shared__ float hbuf[FINAL ? 8 : 1][FINAL ? HID : 1];
    if (FINAL) {
        for (int i = threadIdx.x; i < CLS * HID; i += 256)
            WlT[(i & (HID - 1)) * CLS + (i >> 6)] = OW[i];
        if (threadIdx.x < CLS) Bl[threadIdx.x] = OB[threadIdx.x];
        __syncthreads();
    }
    int cpy = blockIdx.x & (R - 1);
    const __half* Hh = HhR + (size_t)cpy * hN;
    const __half* wg = wgtR + (size_t)cpy * wN;
    int wid = threadIdx.x >> 6;
    int lane = threadIdx.x & 63;
    int half = lane >> 5;
    int l32 = lane & 31;
    int halfId = threadIdx.x >> 5;  // 0..7
    int node = (blockIdx.x * 4 + wid) * 2 + half;
    bool nvalid = node < n;
    int beg = 0, deg = 0;
    if (nvalid) { beg = offD[node]; deg = offD[node + 1] - beg; }
    int degOther = __shfl(deg, lane ^ 32);
    int maxdeg = max(deg, degOther);
    float ml0 = -INFINITY, ml1 = -INFINITY, ml2 = -INFINITY, ml3 = -INFINITY;
    float mh0 = -INFINITY, mh1 = -INFINITY, mh2 = -INFINITY, mh3 = -INFINITY;
    for (int base = 0; base < maxdeg; base += 32) {
        int idx = base + l32;
        int s = 0;
        float wv = 0.f;
        if (idx < deg) {
            int2 c = csrD[beg + idx];
            s = c.x;
            wv = __half2float(wg[c.y]);
        }
        int cnt = min(32, maxdeg - base);
        int cnt4 = cnt & ~3;
        int bl = half << 5;
        for (int j = 0; j < cnt4; j += 4) {
            int s0 = __shfl(s, bl + j),     s1 = __shfl(s, bl + j + 1),
                s2 = __shfl(s, bl + j + 2), s3 = __shfl(s, bl + j + 3);
            float w0 = __shfl(wv, bl + j),     w1 = __shfl(wv, bl + j + 1),
                  w2 = __shfl(wv, bl + j + 2), w3 = __shfl(wv, bl + j + 3);
            float hl0 = __half2float(Hh[(size_t)s0 * HID + l32]);
            float hh0 = __half2float(Hh[(size_t)s0 * HID + 32 + l32]);
            float hl1 = __half2float(Hh[(size_t)s1 * HID + l32]);
            float hh1 = __half2float(Hh[(size_t)s1 * HID + 32 + l32]);
            float hl2 = __half2float(Hh[(size_t)s2 * HID + l32]);
            float hh2 = __half2float(Hh[(size_t)s2 * HID + 32 + l32]);
            float hl3 = __half2float(Hh[(size_t)s3 * HID + l32]);
            float hh3 = __half2float(Hh[(size_t)s3 * HID + 32 + l32]);
            if (base + j < deg)     { ml0 = fmaxf(ml0, w0 * hl0); mh0 = fmaxf(mh0, w0 * hh0); }
            if (base + j + 1 < deg) { ml1 = fmaxf(ml1, w1 * hl1); mh1 = fmaxf(mh1, w1 * hh1); }
            if (base + j + 2 < deg) { ml2 = fmaxf(ml2, w2 * hl2); mh2 = fmaxf(mh2, w2 * hh2); }
            if (base + j + 3 < deg) { ml3 = fmaxf(ml3, w3 * hl3); mh3 = fmaxf(mh3, w3 * hh3); }
        }
        for (int j = cnt4; j < cnt; j++) {
            int sj = __shfl(s, bl + j);
            float wj = __shfl(wv, bl + j);
            float hl = __half2float(Hh[(size_t)sj * HID + l32]);
            float hh = __half2float(Hh[(size_t)sj * HID + 32 + l32]);
            if (base + j < deg) { ml0 = fmaxf(ml0, wj * hl); mh0 = fmaxf(mh0, wj * hh); }
        }
    }
    float mlo = fmaxf(fmaxf(ml0, ml1), fmaxf(ml2, ml3));
    float mhi = fmaxf(fmaxf(mh0, mh1), fmaxf(mh2, mh3));
    float vlo = fmaxf(mlo + bias[l32], 0.f);
    float vhi = fmaxf(mhi + bias[32 + l32], 0.f);
    if (!FINAL) {
        if (nvalid) {
            outH[(size_t)node * HID + l32] = __float2half(vlo);
            outH[(size_t)node * HID + 32 + l32] = __float2half(vhi);
        }
    } else {
        hbuf[halfId][l32] = nvalid ? vlo : 0.f;
        hbuf[halfId][32 + l32] = nvalid ? vhi : 0.f;
        __syncthreads();
        float lg1 = Bl[l32];
        float lg2 = (l32 < 8) ? Bl[32 + l32] : -INFINITY;
        for (int k = 0; k < HID; k++) {
            float hv = hbuf[halfId][k];          // broadcast
            lg1 += hv * WlT[k * CLS + l32];      // stride-1: conflict-free
            if (l32 < 8) lg2 += hv * WlT[k * CLS + 32 + l32];
        }
        float m = wmax32(fmaxf(lg1, lg2));
        float ssum = wsum32(expf(lg1 - m) + ((l32 < 8) ? expf(lg2 - m) : 0.f));
        float lse = m + logf(ssum);
        if (nvalid) {
            outF[(size_t)node * CLS + l32] = lg1 - lse;
            if (l32 < 8) outF[(size_t)node * CLS + 32 + l32] = lg2 - lse;
        }
    }
}

extern "C" void kernel_launch(void* const* d_in, const int* in_sizes, int n_in,
                              void* d_out, int out_size, void* d_ws, size_t ws_size,
                              hipStream_t stream) {
    const float* x   = (const float*)d_in[0];
    const int*   ei  = (const int*)d_in[1];
    const float* nrm = (const float*)d_in[2];
    const float* w0  = (const float*)d_in[3];
    const float* w1  = (const float*)d_in[4];
    const float* aw0 = (const float*)d_in[5];
    const float* ab0 = (const float*)d_in[6];
    const float* aw1 = (const float*)d_in[7];
    const float* ab1 = (const float*)d_in[8];
    const float* sw0 = (const float*)d_in[9];
    const float* sb0 = (const float*)d_in[10];
    const float* sw1 = (const float*)d_in[11];
    const float* sb1 = (const float*)d_in[12];
    const float* al0 = (const float*)d_in[13];
    const float* al1 = (const float*)d_in[14];
    const float* b0  = (const float*)d_in[15];
    const float* b1  = (const float*)d_in[16];
    const float* ow  = (const float*)d_in[17];
    const float* ob  = (const float*)d_in[18];
    float* out = (float*)d_out;

    int N = in_sizes[0] / 128;
    int E = in_sizes[1] / 2;
    int Et = E + N;

    char* base = (char*)d_ws;
    size_t off = 0;
    auto alloc = [&](size_t bytes) {
        void* p = base + off;
        off += (bytes + 255) & ~(size_t)255;
        return p;
    };
    int* degS = (int*)alloc(N * 4);
    int* degD = (int*)alloc(N * 4);
    int* offS = (int*)alloc((N + 1) * 4);
    int* offD = (int*)alloc((N + 1) * 4);
    int* bsum = (int*)alloc(128 * 4);
    unsigned* ranks = (unsigned*)alloc((size_t)E * 4);
    int2* slots = (int2*)alloc((size_t)Et * 8);
    int2* csrS = (int2*)alloc((size_t)Et * 8);
    int2* csrD = (int2*)alloc((size_t)Et * 8);
    float* ds    = (float*)alloc(N * 4);
    float* dssw  = (float*)alloc(N * 4);
    float* dtraw = (float*)alloc(N * 4);
    float* d2raw = (float*)alloc(N * 4);
    float* d3raw = (float*)alloc(N * 4);
    float2* dtp  = (float2*)alloc((size_t)N * 8 * 8);   // 8 XCD-local copies
    __half* layh = (__half*)alloc((size_t)N * HID * 2); // fp16 layer-0 output

    // replication factor for H and wgt: as many XCD-local copies as fit (pow2, <=8)
    size_t hbytes = (size_t)N * HID * 2;
    size_t wbytes = (size_t)Et * 2;
    size_t rem = (ws_size > off) ? ws_size - off : (hbytes + wbytes);
    int R = 1;
    while (R < 8 && (size_t)(2 * R) * (hbytes + wbytes) <= rem) R <<= 1;
    __half* HhR  = (__half*)alloc(hbytes * R);
    __half* wgtR = (__half*)alloc(wbytes * R);
    size_t hN = (size_t)N * HID;

    int nbScan = (N + 1023) / 1024;
    int nbW2 = (N + 7) / 8;     // aggr: 2 nodes/wave, 4 waves/block
    int nbS = (N + 7) / 8;      // soft: 2 nodes/wave (32 lanes each)
    int gb = (N + 63) / 64;     // gemm blocks (64 rows each)
    int cnb = (E + 1023) / 1024;

    hipMemsetAsync(degS, 0, (size_t)N * 4, stream);
    hipMemsetAsync(degD, 0, (size_t)N * 4, stream);
    k_fused0<<<gb + cnb, 256, 0, stream>>>(x, w0, aw0, sw0, HhR, hN, R, ds,
                                           dtraw, d2raw, d3raw,
                                           ei, degS, degD, ranks, N, E, gb);
    k_scanA<<<2 * nbScan, 1024, 0, stream>>>(degS, degD, d2raw, d3raw, dtraw,
                                             offS, offD, bsum, dssw, dtp,
                                             N, nbScan);
    k_scanC<<<2 * nbScan, 1024, 0, stream>>>(degS, degD, offS, offD, bsum,
                                             N, Et, nbScan);
    k_slots<<<(Et + 255) / 256, 256, 0, stream>>>(ei, ranks, offS, offD,
                                                  slots, Et, E);
    k_scatter<<<2048, 256, 0, stream>>>(ei, nrm, slots, offS, offD,
                                        csrS, csrD, Et, E, N);

    // layer 0
    k_soft<<<nbS, 256, 0, stream>>>(offS, csrS, ds, dssw, dtp,
                                    ab0, sb0, al0, wgtR, Et, R, N);
    k_aggr<false><<<nbW2, 256, 0, stream>>>(offD, csrD, wgtR, Et, HhR, hN, R,
                                            b0, nullptr, nullptr, layh, nullptr, N);

    // layer 1
    k_gemm1<<<gb, 256, 0, stream>>>(layh, w1, aw1, sw1, degS, degD,
                                    HhR, hN, R, ds, dssw, dtp, N);
    k_soft<<<nbS, 256, 0, stream>>>(offS, csrS, ds, dssw, dtp,
                                    ab1, sb1, al1, wgtR, Et, R, N);
    k_aggr<true><<<nbW2, 256, 0, stream>>>(offD, csrD, wgtR, Et, HhR, hN, R,
                                           b1, ow, ob, nullptr, out, N);
}

// Round 12
// 258.367 us; speedup vs baseline: 1.3778x; 1.0173x over previous
//
#include <hip/hip_runtime.h>
#include <hip/hip_fp16.h>
#include <cstddef>

#define HID 64
#define CLS 40

__device__ __forceinline__ float lrelu(float x) { return x >= 0.f ? x : 0.2f * x; }

__device__ __forceinline__ float wmax32(float v) {
#pragma unroll
    for (int o = 16; o > 0; o >>= 1) v = fmaxf(v, __shfl_xor(v, o));
    return v;
}
__device__ __forceinline__ float wsum32(float v) {
#pragma unroll
    for (int o = 16; o > 0; o >>= 1) v += __shfl_xor(v, o);
    return v;
}

// ---------------- GEMM body: 64 rows/block, 4 threads/row ----------------
// W staged in LDS, row stride K+4, seg-interleaved columns (2-way conflict = free).
// X dtype templated (fp32 layer 0, fp16 layer 1). Writes R replicated fp16 H copies.
template <int K, bool APPLY, typename XT>
__device__ __forceinline__ void gemm_body(const XT* __restrict__ X,
                                          const float* __restrict__ W,
                                          const float* __restrict__ aw,
                                          const float* __restrict__ sw,
                                          const int* __restrict__ degS,
                                          const int* __restrict__ degD,
                                          __half* __restrict__ Hh, size_t hN, int R,
                                          float* __restrict__ ds,
                                          float* __restrict__ dssw,
                                          float2* __restrict__ dtp,
                                          float* __restrict__ dtraw,
                                          float* __restrict__ d2raw,
                                          float* __restrict__ d3raw,
                                          int n, int brow, int tid) {
    constexpr int STR = K + 4;
    __shared__ float Wl[HID * STR];
    __shared__ float awl[128];
    __shared__ float swl[128];
    for (int i = tid; i < HID * K; i += 256) {
        int c = i / K, k = i % K;
        Wl[c * STR + k] = W[i];
    }
    if (tid < 128) awl[tid] = aw[tid];
    else swl[tid - 128] = sw[tid - 128];
    __syncthreads();
    int r = brow * 64 + (tid >> 2);
    int seg = tid & 3;
    if (r >= n) return;
    float acc[16];
#pragma unroll
    for (int c = 0; c < 16; c++) acc[c] = 0.f;
    const XT* xr = X + (size_t)r * K;
    const float* wb = &Wl[4 * seg * STR];
    for (int k = 0; k < K; k += 4) {
        float4 xv;
        if constexpr (sizeof(XT) == 4) {
            xv = *reinterpret_cast<const float4*>(xr + k);
        } else {
            __half2 a = *reinterpret_cast<const __half2*>(xr + k);
            __half2 b = *reinterpret_cast<const __half2*>(xr + k + 2);
            xv = make_float4(__low2float(a), __high2float(a),
                             __low2float(b), __high2float(b));
        }
#pragma unroll
        for (int c = 0; c < 16; c++) {
            int crel = 16 * (c >> 2) + (c & 3);
            float4 wv = *reinterpret_cast<const float4*>(wb + crel * STR + k);
            acc[c] += xv.x * wv.x + xv.y * wv.y + xv.z * wv.z + xv.w * wv.w;
        }
    }
    float d0 = 0.f, d1 = 0.f, d2 = 0.f, d3 = 0.f;
#pragma unroll
    for (int c = 0; c < 16; c++) {
        int cc = 16 * (c >> 2) + 4 * seg + (c & 3);
        d0 += acc[c] * awl[cc];
        d1 += acc[c] * awl[64 + cc];
        d2 += acc[c] * swl[cc];
        d3 += acc[c] * swl[64 + cc];
    }
    uint2 stv[4];
#pragma unroll
    for (int t = 0; t < 4; t++) {
        union { __half2 h2[2]; uint2 u; } st;
        st.h2[0] = __floats2half2_rn(acc[4 * t], acc[4 * t + 1]);
        st.h2[1] = __floats2half2_rn(acc[4 * t + 2], acc[4 * t + 3]);
        stv[t] = st.u;
    }
    for (int rep = 0; rep < R; rep++) {
        __half* hb = Hh + (size_t)rep * hN + (size_t)r * HID + 4 * seg;
#pragma unroll
        for (int t = 0; t < 4; t++)
            *reinterpret_cast<uint2*>(hb + 16 * t) = stv[t];
    }
    // quad reduce (threads 4q..4q+3 share row r)
    d0 += __shfl_xor(d0, 1); d0 += __shfl_xor(d0, 2);
    d1 += __shfl_xor(d1, 1); d1 += __shfl_xor(d1, 2);
    d2 += __shfl_xor(d2, 1); d2 += __shfl_xor(d2, 2);
    d3 += __shfl_xor(d3, 1); d3 += __shfl_xor(d3, 2);
    if (seg == 0) {
        ds[r] = d0;
        if (APPLY) {
            dssw[r] = (float)(degS[r] + 1) * d2;
            float2 v = make_float2(d1, (float)(degD[r] + 1) * d3);
            for (int rep = 0; rep < 8; rep++) dtp[(size_t)rep * n + r] = v;
        } else {
            dtraw[r] = d1;
            d2raw[r] = d2;
            d3raw[r] = d3;
        }
    }
}

// ---------------- fused: layer-0 GEMM (independent) + degree count/rank ----------------
__global__ __launch_bounds__(256) void k_fused0(const float* __restrict__ x,
                                                const float* __restrict__ w0,
                                                const float* __restrict__ aw,
                                                const float* __restrict__ sw,
                                                __half* __restrict__ Hh, size_t hN, int R,
                                                float* __restrict__ ds,
                                                float* __restrict__ dtraw,
                                                float* __restrict__ d2raw,
                                                float* __restrict__ d3raw,
                                                const int* __restrict__ ei,
                                                int* degS, int* degD,
                                                unsigned* __restrict__ ranks,
                                                int n, int E, int gb) {
    if ((int)blockIdx.x < gb) {
        gemm_body<128, false, float>(x, w0, aw, sw, nullptr, nullptr, Hh, hN, R, ds,
                                     nullptr, nullptr, dtraw, d2raw, d3raw,
                                     n, blockIdx.x, threadIdx.x);
    } else {
        int t = (blockIdx.x - gb) * 256 + threadIdx.x;
        int stride = (gridDim.x - gb) * 256;
        for (int e = t; e < E; e += stride) {
            int s = ei[e], d = ei[E + e];
            unsigned rs = (unsigned)atomicAdd(&degS[s], 1);
            unsigned rd = (unsigned)atomicAdd(&degD[d], 1);
            ranks[e] = rs | (rd << 16);  // deg < 65536
        }
    }
}

// ---------------- layer-1 GEMM (fp16 input) ----------------
__global__ __launch_bounds__(256) void k_gemm1(const __half* __restrict__ X,
                                               const float* __restrict__ W,
                                               const float* __restrict__ aw,
                                               const float* __restrict__ sw,
                                               const int* __restrict__ degS,
                                               const int* __restrict__ degD,
                                               __half* __restrict__ Hh, size_t hN, int R,
                                               float* __restrict__ ds,
                                               float* __restrict__ dssw,
                                               float2* __restrict__ dtp,
                                               int n) {
    gemm_body<64, true, __half>(X, W, aw, sw, degS, degD, Hh, hN, R, ds, dssw, dtp,
                                nullptr, nullptr, nullptr, n, blockIdx.x, threadIdx.x);
}

// ---------------- combined scans: S (blocks 0..nb-1) and D (nb..2nb-1) ----------------
__global__ __launch_bounds__(1024) void k_scanA(const int* __restrict__ degS,
                                                const int* __restrict__ degD,
                                                const float* __restrict__ d2raw,
                                                const float* __restrict__ d3raw,
                                                const float* __restrict__ dtraw,
                                                int* __restrict__ offS,
                                                int* __restrict__ offD,
                                                int* __restrict__ bsum,
                                                float* __restrict__ dssw,
                                                float2* __restrict__ dtp,
                                                int n, int nb) {
    __shared__ int buf[2][1024];
    int which = (int)blockIdx.x >= nb;
    const int* deg = which ? degD : degS;
    int* off = which ? offD : offS;
    int b = blockIdx.x - (which ? nb : 0);
    int tid = threadIdx.x;
    int i = b * 1024 + tid;
    int v = (i < n) ? deg[i] + 1 : 0;
    int cur = 0;
    buf[0][tid] = v;
    __syncthreads();
#pragma unroll
    for (int o = 1; o < 1024; o <<= 1) {
        int t = buf[cur][tid];
        if (tid >= o) t += buf[cur][tid - o];
        buf[cur ^ 1][tid] = t;
        cur ^= 1;
        __syncthreads();
    }
    if (i < n) off[i] = buf[cur][tid];
    if (tid == 1023) bsum[which * 64 + b] = buf[cur][1023];
    if (!which && i < n) {
        dssw[i] = (float)(degS[i] + 1) * d2raw[i];
        float2 vv = make_float2(dtraw[i], (float)(degD[i] + 1) * d3raw[i]);
        for (int rep = 0; rep < 8; rep++) dtp[(size_t)rep * n + i] = vv;
    }
}

// scanC with inlined block-sum prefix
__global__ __launch_bounds__(1024) void k_scanC(const int* __restrict__ degS,
                                                const int* __restrict__ degD,
                                                int* __restrict__ offS,
                                                int* __restrict__ offD,
                                                const int* __restrict__ bsum,
                                                int n, int total, int nb) {
    __shared__ int basesum;
    int which = (int)blockIdx.x >= nb;
    const int* deg = which ? degD : degS;
    int* off = which ? offD : offS;
    int b = blockIdx.x - (which ? nb : 0);
    if (threadIdx.x < 64) {
        int v = ((int)threadIdx.x < b) ? bsum[which * 64 + threadIdx.x] : 0;
#pragma unroll
        for (int o = 32; o > 0; o >>= 1) v += __shfl_xor(v, o);
        if (threadIdx.x == 0) basesum = v;
    }
    __syncthreads();
    int i = b * 1024 + threadIdx.x;
    if (i < n) off[i] = off[i] - (deg[i] + 1) + basesum;
    if (i == 0) off[n] = total;
}

// ---------------- slots pre-pass: slot = off[node] + rank, computed ONCE ----------------
__global__ __launch_bounds__(256) void k_slots(const int* __restrict__ ei,
                                               const unsigned* __restrict__ ranks,
                                               const int* __restrict__ offS,
                                               const int* __restrict__ offD,
                                               int2* __restrict__ slots,
                                               int Et, int E) {
    int e = blockIdx.x * 256 + threadIdx.x;
    if (e >= Et) return;
    if (e < E) {
        int s = ei[e], d = ei[E + e];
        unsigned ur = ranks[e];
        slots[e] = make_int2(offS[s] + (int)(ur & 0xffffu),
                             offD[d] + (int)(ur >> 16));
    } else {
        int v = e - E;  // self-loop: LAST slot of each segment
        slots[e] = make_int2(offS[v + 1] - 1, offD[v + 1] - 1);
    }
}

// ---------------- scatter: XCD-partitioned via slot-range test ----------------
// csrS[slotS] = {dst, norm_bits};  csrD[slotD] = {src, slotS}
__global__ __launch_bounds__(256) void k_scatter(const int* __restrict__ ei,
                                                 const float* __restrict__ norm,
                                                 const int2* __restrict__ slots,
                                                 const int* __restrict__ offS,
                                                 const int* __restrict__ offD,
                                                 int2* __restrict__ csrS,
                                                 int2* __restrict__ csrD,
                                                 int Et, int E, int N) {
    int grp = blockIdx.x & 7;
    int lo = (int)(((long long)grp * N) / 8);
    int hi = (int)(((long long)(grp + 1) * N) / 8);
    int sLo = offS[lo], sHi = offS[hi];
    int dLo = offD[lo], dHi = offD[hi];
    int start = (blockIdx.x >> 3) * 256 + threadIdx.x;
    int stride = (gridDim.x >> 3) * 256;
    for (int e = start; e < Et; e += stride) {
        int2 sl = slots[e];
        bool doS = (sl.x >= sLo) & (sl.x < sHi);
        bool doD = (sl.y >= dLo) & (sl.y < dHi);
        if (doS | doD) {
            int nb = __float_as_int(norm[e]);
            if (doS) {
                int d = (e < E) ? ei[E + e] : e - E;
                csrS[sl.x] = make_int2(d, nb);
            }
            if (doD) {
                int s = (e < E) ? ei[e] : e - E;
                csrD[sl.y] = make_int2(s, sl.x);
            }
        }
    }
}

// ---------------- softmax by src: 32 lanes/node, writes R fp16 weight copies ----------------
__global__ __launch_bounds__(256) void k_soft(const int* __restrict__ offS,
                                              const int2* __restrict__ csrS,
                                              const float* __restrict__ ds,
                                              const float* __restrict__ dssw,
                                              const float2* __restrict__ dtp,
                                              const float* __restrict__ ab,
                                              const float* __restrict__ sb,
                                              const float* __restrict__ alpha,
                                              __half* __restrict__ wgtR, int wN, int R,
                                              int n) {
    const float2* dtpc = dtp + (size_t)(blockIdx.x & 7) * n;
    int node = blockIdx.x * 8 + (threadIdx.x >> 5);
    int lane = threadIdx.x & 31;
    if (node >= n) return;
    int beg = offS[node];
    int deg = offS[node + 1] - beg;
    float ds_s = ds[node], dssw_s = dssw[node];
    float ab0 = ab[0], sb0 = sb[0], al = alpha[0];

    if (deg <= 32) {
        bool valid = lane < deg;
        float sim = -INFINITY, nsim = -INFINITY;
        int pos = beg + lane;
        if (valid) {
            int2 c = csrS[pos];
            float nr = __int_as_float(c.y);
            float2 p = dtpc[c.x];
            sim = lrelu(nr * (ds_s + p.x) + ab0);
            nsim = lrelu(dssw_s + p.y + sb0);
        }
        float mAv = wmax32(sim), mNv = wmax32(nsim);
        float eA = valid ? expf(sim - mAv) : 0.f;
        float eN = valid ? expf(nsim - mNv) : 0.f;
        float sAv = wsum32(eA), sNv = wsum32(eN);
        if (valid) {
            __half hv = __float2half(al * eA / sAv + (1.f - al) * eN / sNv);
            for (int rep = 0; rep < R; rep++) wgtR[(size_t)rep * wN + pos] = hv;
        }
    } else {
        float mAv = -INFINITY, mNv = -INFINITY;
        for (int base = 0; base < deg; base += 32) {
            int idx = base + lane;
            if (idx < deg) {
                int2 c = csrS[beg + idx];
                float nr = __int_as_float(c.y);
                float2 p = dtpc[c.x];
                mAv = fmaxf(mAv, lrelu(nr * (ds_s + p.x) + ab0));
                mNv = fmaxf(mNv, lrelu(dssw_s + p.y + sb0));
            }
        }
        mAv = wmax32(mAv);
        mNv = wmax32(mNv);
        float a = 0.f, bb = 0.f;
        for (int base = 0; base < deg; base += 32) {
            int idx = base + lane;
            if (idx < deg) {
                int2 c = csrS[beg + idx];
                float nr = __int_as_float(c.y);
                float2 p = dtpc[c.x];
                a += expf(lrelu(nr * (ds_s + p.x) + ab0) - mAv);
                bb += expf(lrelu(dssw_s + p.y + sb0) - mNv);
            }
        }
        float sAv = wsum32(a);
        float sNv = wsum32(bb);
        for (int base = 0; base < deg; base += 32) {
            int idx = base + lane;
            if (idx < deg) {
                int2 c = csrS[beg + idx];
                float nr = __int_as_float(c.y);
                float2 p = dtpc[c.x];
                float eA = expf(lrelu(nr * (ds_s + p.x) + ab0) - mAv);
                float eN = expf(lrelu(dssw_s + p.y + sb0) - mNv);
                __half hv = __float2half(al * eA / sAv + (1.f - al) * eN / sNv);
                for (int rep = 0; rep < R; rep++)
                    wgtR[(size_t)rep * wN + beg + idx] = hv;
            }
        }
    }
}

// ---------------- aggregation by dst: 32 lanes/node, 2 nodes/wave ----------------
// Lane owns components {2l, 2l+1}: one half2 load per (edge,lane).
// FINAL=false: write fp16 layer output. FINAL=true: fuse logits + log_softmax.
template <bool FINAL>
__global__ __launch_bounds__(256) void k_aggr(const int* __restrict__ offD,
                                              const int2* __restrict__ csrD,
                                              const __half* __restrict__ wgtR, int wN,
                                              const __half* __restrict__ HhR, size_t hN,
                                              int R,
                                              const float* __restrict__ bias,
                                              const float* __restrict__ OW,
                                              const float* __restrict__ OB,
                                              __half* __restrict__ outH,
                                              float* __restrict__ outF, int n) {
    __shared__ float WlT[FINAL ? HID * CLS : 1];  // transposed: WlT[k*CLS+c]
    __shared__ float Bl[FINAL ? CLS : 1];
    __shared__ float hbuf[FINAL ? 8 : 1][FINAL ? HID : 1];
    if (FINAL) {
        for (int i = threadIdx.x; i < CLS * HID; i += 256)
            WlT[(i & (HID - 1)) * CLS + (i >> 6)] = OW[i];
        if (threadIdx.x < CLS) Bl[threadIdx.x] = OB[threadIdx.x];
        __syncthreads();
    }
    int cpy = blockIdx.x & (R - 1);
    const __half* Hh = HhR + (size_t)cpy * hN;
    const __half* wg = wgtR + (size_t)cpy * wN;
    int wid = threadIdx.x >> 6;
    int lane = threadIdx.x & 63;
    int half = lane >> 5;
    int l32 = lane & 31;
    int halfId = threadIdx.x >> 5;  // 0..7
    int node = (blockIdx.x * 4 + wid) * 2 + half;
    bool nvalid = node < n;
    int beg = 0, deg = 0;
    if (nvalid) { beg = offD[node]; deg = offD[node + 1] - beg; }
    int degOther = __shfl(deg, lane ^ 32);
    int maxdeg = max(deg, degOther);
    float b0v = bias[2 * l32], b1v = bias[2 * l32 + 1];
    float me0 = -INFINITY, me1 = -INFINITY, me2 = -INFINITY, me3 = -INFINITY;
    float mo0 = -INFINITY, mo1 = -INFINITY, mo2 = -INFINITY, mo3 = -INFINITY;
    for (int base = 0; base < maxdeg; base += 32) {
        int idx = base + l32;
        int s = 0;
        float wv = 0.f;
        if (idx < deg) {
            int2 c = csrD[beg + idx];
            s = c.x;
            wv = __half2float(wg[c.y]);
        }
        int cnt = min(32, maxdeg - base);
        int cnt4 = cnt & ~3;
        int bl = half << 5;
        for (int j = 0; j < cnt4; j += 4) {
            int s0 = __shfl(s, bl + j),     s1 = __shfl(s, bl + j + 1),
                s2 = __shfl(s, bl + j + 2), s3 = __shfl(s, bl + j + 3);
            float w0 = __shfl(wv, bl + j),     w1 = __shfl(wv, bl + j + 1),
                  w2 = __shfl(wv, bl + j + 2), w3 = __shfl(wv, bl + j + 3);
            float2 f0 = __half22float2(*reinterpret_cast<const __half2*>(
                Hh + (size_t)s0 * HID + 2 * l32));
            float2 f1 = __half22float2(*reinterpret_cast<const __half2*>(
                Hh + (size_t)s1 * HID + 2 * l32));
            float2 f2 = __half22float2(*reinterpret_cast<const __half2*>(
                Hh + (size_t)s2 * HID + 2 * l32));
            float2 f3 = __half22float2(*reinterpret_cast<const __half2*>(
                Hh + (size_t)s3 * HID + 2 * l32));
            if (base + j < deg)     { me0 = fmaxf(me0, w0 * f0.x); mo0 = fmaxf(mo0, w0 * f0.y); }
            if (base + j + 1 < deg) { me1 = fmaxf(me1, w1 * f1.x); mo1 = fmaxf(mo1, w1 * f1.y); }
            if (base + j + 2 < deg) { me2 = fmaxf(me2, w2 * f2.x); mo2 = fmaxf(mo2, w2 * f2.y); }
            if (base + j + 3 < deg) { me3 = fmaxf(me3, w3 * f3.x); mo3 = fmaxf(mo3, w3 * f3.y); }
        }
        for (int j = cnt4; j < cnt; j++) {
            int sj = __shfl(s, bl + j);
            float wj = __shfl(wv, bl + j);
            float2 f = __half22float2(*reinterpret_cast<const __half2*>(
                Hh + (size_t)sj * HID + 2 * l32));
            if (base + j < deg) { me0 = fmaxf(me0, wj * f.x); mo0 = fmaxf(mo0, wj * f.y); }
        }
    }
    float me = fmaxf(fmaxf(me0, me1), fmaxf(me2, me3));
    float mo = fmaxf(fmaxf(mo0, mo1), fmaxf(mo2, mo3));
    float v0 = fmaxf(me + b0v, 0.f);
    float v1 = fmaxf(mo + b1v, 0.f);
    if (!FINAL) {
        if (nvalid)
            *reinterpret_cast<__half2*>(outH + (size_t)node * HID + 2 * l32) =
                __floats2half2_rn(v0, v1);
    } else {
        hbuf[halfId][2 * l32] = nvalid ? v0 : 0.f;
        hbuf[halfId][2 * l32 + 1] = nvalid ? v1 : 0.f;
        __syncthreads();
        float lg1 = Bl[l32];
        float lg2 = (l32 < 8) ? Bl[32 + l32] : -INFINITY;
        for (int k = 0; k < HID; k++) {
            float hv = hbuf[halfId][k];          // broadcast
            lg1 += hv * WlT[k * CLS + l32];      // stride-1: conflict-free
            if (l32 < 8) lg2 += hv * WlT[k * CLS + 32 + l32];
        }
        float m = wmax32(fmaxf(lg1, lg2));
        float ssum = wsum32(expf(lg1 - m) + ((l32 < 8) ? expf(lg2 - m) : 0.f));
        float lse = m + logf(ssum);
        if (nvalid) {
            outF[(size_t)node * CLS + l32] = lg1 - lse;
            if (l32 < 8) outF[(size_t)node * CLS + 32 + l32] = lg2 - lse;
        }
    }
}

extern "C" void kernel_launch(void* const* d_in, const int* in_sizes, int n_in,
                              void* d_out, int out_size, void* d_ws, size_t ws_size,
                              hipStream_t stream) {
    const float* x   = (const float*)d_in[0];
    const int*   ei  = (const int*)d_in[1];
    const float* nrm = (const float*)d_in[2];
    const float* w0  = (const float*)d_in[3];
    const float* w1  = (const float*)d_in[4];
    const float* aw0 = (const float*)d_in[5];
    const float* ab0 = (const float*)d_in[6];
    const float* aw1 = (const float*)d_in[7];
    const float* ab1 = (const float*)d_in[8];
    const float* sw0 = (const float*)d_in[9];
    const float* sb0 = (const float*)d_in[10];
    const float* sw1 = (const float*)d_in[11];
    const float* sb1 = (const float*)d_in[12];
    const float* al0 = (const float*)d_in[13];
    const float* al1 = (const float*)d_in[14];
    const float* b0  = (const float*)d_in[15];
    const float* b1  = (const float*)d_in[16];
    const float* ow  = (const float*)d_in[17];
    const float* ob  = (const float*)d_in[18];
    float* out = (float*)d_out;

    int N = in_sizes[0] / 128;
    int E = in_sizes[1] / 2;
    int Et = E + N;

    char* base = (char*)d_ws;
    size_t off = 0;
    auto alloc = [&](size_t bytes) {
        void* p = base + off;
        off += (bytes + 255) & ~(size_t)255;
        return p;
    };
    size_t padN4 = ((size_t)N * 4 + 255) & ~(size_t)255;
    int* degS = (int*)alloc(N * 4);
    int* degD = (int*)alloc(N * 4);
    int* offS = (int*)alloc((N + 1) * 4);
    int* offD = (int*)alloc((N + 1) * 4);
    int* bsum = (int*)alloc(128 * 4);
    unsigned* ranks = (unsigned*)alloc((size_t)E * 4);
    int2* slots = (int2*)alloc((size_t)Et * 8);
    int2* csrS = (int2*)alloc((size_t)Et * 8);
    int2* csrD = (int2*)alloc((size_t)Et * 8);
    float* ds    = (float*)alloc(N * 4);
    float* dssw  = (float*)alloc(N * 4);
    float* dtraw = (float*)alloc(N * 4);
    float* d2raw = (float*)alloc(N * 4);
    float* d3raw = (float*)alloc(N * 4);
    float2* dtp  = (float2*)alloc((size_t)N * 8 * 8);   // 8 XCD-local copies
    __half* layh = (__half*)alloc((size_t)N * HID * 2); // fp16 layer-0 output

    // replication factor for H and wgt: as many XCD-local copies as fit (pow2, <=8)
    size_t hbytes = (size_t)N * HID * 2;
    size_t wbytes = (size_t)Et * 2;
    size_t rem = (ws_size > off) ? ws_size - off : (hbytes + wbytes);
    int R = 1;
    while (R < 8 && (size_t)(2 * R) * (hbytes + wbytes) <= rem) R <<= 1;
    __half* HhR  = (__half*)alloc(hbytes * R);
    __half* wgtR = (__half*)alloc(wbytes * R);
    size_t hN = (size_t)N * HID;
    int wN = Et;

    int nbScan = (N + 1023) / 1024;
    int nbW2 = (N + 7) / 8;     // aggr: 2 nodes/wave, 4 waves/block
    int nbS = (N + 7) / 8;      // soft: 2 nodes/wave (32 lanes each)
    int gb = (N + 63) / 64;     // gemm blocks (64 rows each)
    int cnb = (E + 1023) / 1024;

    hipMemsetAsync(degS, 0, 2 * padN4, stream);  // degS+degD contiguous
    k_fused0<<<gb + cnb, 256, 0, stream>>>(x, w0, aw0, sw0, HhR, hN, R, ds,
                                           dtraw, d2raw, d3raw,
                                           ei, degS, degD, ranks, N, E, gb);
    k_scanA<<<2 * nbScan, 1024, 0, stream>>>(degS, degD, d2raw, d3raw, dtraw,
                                             offS, offD, bsum, dssw, dtp,
                                             N, nbScan);
    k_scanC<<<2 * nbScan, 1024, 0, stream>>>(degS, degD, offS, offD, bsum,
                                             N, Et, nbScan);
    k_slots<<<(Et + 255) / 256, 256, 0, stream>>>(ei, ranks, offS, offD,
                                                  slots, Et, E);
    k_scatter<<<2048, 256, 0, stream>>>(ei, nrm, slots, offS, offD,
                                        csrS, csrD, Et, E, N);

    // layer 0
    k_soft<<<nbS, 256, 0, stream>>>(offS, csrS, ds, dssw, dtp,
                                    ab0, sb0, al0, wgtR, wN, R, N);
    k_aggr<false><<<nbW2, 256, 0, stream>>>(offD, csrD, wgtR, wN, HhR, hN, R,
                                            b0, nullptr, nullptr, layh, nullptr, N);

    // layer 1
    k_gemm1<<<gb, 256, 0, stream>>>(layh, w1, aw1, sw1, degS, degD,
                                    HhR, hN, R, ds, dssw, dtp, N);
    k_soft<<<nbS, 256, 0, stream>>>(offS, csrS, ds, dssw, dtp,
                                    ab1, sb1, al1, wgtR, wN, R, N);
    k_aggr<true><<<nbW2, 256, 0, stream>>>(offD, csrD, wgtR, wN, HhR, hN, R,
                                           b1, ow, ob, nullptr, out, N);
}